// Round 1
// baseline (1606.314 us; speedup 1.0000x reference)
//
#include <hip/hip_runtime.h>
#include <hip/hip_bf16.h>
#include <math.h>

#define DM    768
#define NH    12
#define DK    64
#define DFF   3072
#define BATCH 2
#define SLEN  2048
#define MTOT  (BATCH*SLEN)   // 4096
#define LNEPS 1e-6f

// ---------------------------------------------------------------------------
// LayerNorm: one block per row (768 cols, 256 threads, 3 elems/thread).
// torch-style: std with Bessel correction (ddof=1), scalar alpha/bias.
// ---------------------------------------------------------------------------
__global__ __launch_bounds__(256) void ln_kernel(const float* __restrict__ x,
                                                 float* __restrict__ out,
                                                 const float* __restrict__ alpha_p,
                                                 const float* __restrict__ beta_p) {
    int row = blockIdx.x;
    const float* xr = x + (size_t)row * DM;
    int t = threadIdx.x;
    float v0 = xr[t], v1 = xr[t + 256], v2 = xr[t + 512];
    float s = v0 + v1 + v2;
    #pragma unroll
    for (int off = 32; off > 0; off >>= 1) s += __shfl_down(s, off);
    __shared__ float red[4];
    __shared__ float red2[4];
    int wv = t >> 6, ln = t & 63;
    if (ln == 0) red[wv] = s;
    __syncthreads();
    float mean = (red[0] + red[1] + red[2] + red[3]) * (1.0f / 768.0f);
    float d0 = v0 - mean, d1 = v1 - mean, d2 = v2 - mean;
    float sq = d0 * d0 + d1 * d1 + d2 * d2;
    #pragma unroll
    for (int off = 32; off > 0; off >>= 1) sq += __shfl_down(sq, off);
    if (ln == 0) red2[wv] = sq;
    __syncthreads();
    float var = (red2[0] + red2[1] + red2[2] + red2[3]) * (1.0f / 767.0f); // ddof=1
    float scale = alpha_p[0] / (sqrtf(var) + LNEPS);
    float bias = beta_p[0];
    float* orow = out + (size_t)row * DM;
    orow[t]       = d0 * scale + bias;
    orow[t + 256] = d1 * scale + bias;
    orow[t + 512] = d2 * scale + bias;
}

// ---------------------------------------------------------------------------
// fp32 SGEMM: C[M,N] = A[M,K] @ W[K,N] + bias (+resid) (+relu)
// BM=BN=128, BK=16, 256 threads (16x16), 8x8 per thread.
// Per-thread N-cols are split {tx*4..+3} and {64+tx*4..+3} so LDS B reads are
// only 2-way bank-aliased (free) instead of 4-way.
// ---------------------------------------------------------------------------
template<bool RELU, bool RESID>
__device__ __forceinline__ void sgemm_body(const float* __restrict__ A,
                                           const float* __restrict__ W,
                                           const float* __restrict__ bias,
                                           const float* __restrict__ resid,
                                           float* __restrict__ C,
                                           int M, int N, int K,
                                           int bm, int bn) {
    __shared__ __align__(16) float As[16][132];  // [k][m], pad 128->132 (2-way writes)
    __shared__ __align__(16) float Bs[16][128];  // [k][n]
    int t = threadIdx.x;
    int tx = t & 15, ty = t >> 4;   // ty 0..15
    int m0 = bm * 128, n0 = bn * 128;
    float acc[8][8];
    #pragma unroll
    for (int i = 0; i < 8; i++)
        #pragma unroll
        for (int j = 0; j < 8; j++) acc[i][j] = 0.f;

    for (int k0 = 0; k0 < K; k0 += 16) {
        // --- stage A tile (128 rows x 16 k), transposed into As[k][m]
        {
            int r = t >> 2;             // 0..63
            int c4 = (t & 3) * 4;       // 0,4,8,12
            #pragma unroll
            for (int p = 0; p < 2; p++) {
                int rr = r + p * 64;
                float4 a = *(const float4*)&A[(size_t)(m0 + rr) * K + k0 + c4];
                As[c4 + 0][rr] = a.x;
                As[c4 + 1][rr] = a.y;
                As[c4 + 2][rr] = a.z;
                As[c4 + 3][rr] = a.w;
            }
            // --- stage B tile (16 k x 128 n)
            int kr = t >> 5;            // 0..7
            int c  = (t & 31) * 4;      // 0..124
            #pragma unroll
            for (int p = 0; p < 2; p++) {
                int kk = kr + p * 8;
                *(float4*)&Bs[kk][c] = *(const float4*)&W[(size_t)(k0 + kk) * N + n0 + c];
            }
        }
        __syncthreads();
        #pragma unroll
        for (int kk = 0; kk < 16; kk++) {
            float a[8], b[8];
            *(float4*)&a[0] = *(const float4*)&As[kk][ty * 8];
            *(float4*)&a[4] = *(const float4*)&As[kk][ty * 8 + 4];
            *(float4*)&b[0] = *(const float4*)&Bs[kk][tx * 4];
            *(float4*)&b[4] = *(const float4*)&Bs[kk][64 + tx * 4];
            #pragma unroll
            for (int i = 0; i < 8; i++)
                #pragma unroll
                for (int j = 0; j < 8; j++)
                    acc[i][j] += a[i] * b[j];
        }
        __syncthreads();
    }
    // --- epilogue
    #pragma unroll
    for (int i = 0; i < 8; i++) {
        int m = m0 + ty * 8 + i;
        #pragma unroll
        for (int half = 0; half < 2; half++) {
            int n = n0 + half * 64 + tx * 4;
            float4 bs = *(const float4*)&bias[n];
            float* a = &acc[i][half * 4];
            float4 r;
            r.x = a[0] + bs.x; r.y = a[1] + bs.y; r.z = a[2] + bs.z; r.w = a[3] + bs.w;
            if (RELU) {
                r.x = fmaxf(r.x, 0.f); r.y = fmaxf(r.y, 0.f);
                r.z = fmaxf(r.z, 0.f); r.w = fmaxf(r.w, 0.f);
            }
            if (RESID) {
                float4 rv = *(const float4*)&resid[(size_t)m * N + n];
                r.x += rv.x; r.y += rv.y; r.z += rv.z; r.w += rv.w;
            }
            *(float4*)&C[(size_t)m * N + n] = r;
        }
    }
}

template<bool RELU, bool RESID>
__global__ __launch_bounds__(256) void sgemm_kernel(const float* __restrict__ A,
                                                    const float* __restrict__ W,
                                                    const float* __restrict__ bias,
                                                    const float* __restrict__ resid,
                                                    float* __restrict__ C,
                                                    int M, int N, int K) {
    sgemm_body<RELU, RESID>(A, W, bias, resid, C, M, N, K, blockIdx.x, blockIdx.y);
}

// Fused QKV: grid.z selects (W, bias, out) so all 3 projections run in one launch.
__global__ __launch_bounds__(256) void qkv_kernel(const float* __restrict__ h,
                                                  const float* __restrict__ wq, const float* __restrict__ bq,
                                                  const float* __restrict__ wk, const float* __restrict__ bk,
                                                  const float* __restrict__ wv, const float* __restrict__ bv,
                                                  float* __restrict__ q, float* __restrict__ k, float* __restrict__ v) {
    int z = blockIdx.z;
    const float* W    = (z == 0) ? wq : (z == 1) ? wk : wv;
    const float* bias = (z == 0) ? bq : (z == 1) ? bk : bv;
    float* out        = (z == 0) ? q  : (z == 1) ? k  : v;
    sgemm_body<false, false>(h, W, bias, nullptr, out, MTOT, DM, DM, blockIdx.x, blockIdx.y);
}

// ---------------------------------------------------------------------------
// Flash attention fp32. Block = 256 threads handles BQ=64 query rows of one
// (b,h); iterates BK=64 key tiles with online softmax. q/k/v are row-major
// [B*S, 768]; per-head slice is the 64-col chunk at h*64 (no transpose needed).
// Thread (rt=t/16, jt=t%16): owns rows {4rt+ri}, score cols {jt+16i} (strided
// so Ks reads are conflict-free), O dims {jt*4+dd}.
// LDS strides: Qs/Ks/Ps = 68 (conflict-free / 2-way), Vs = 64.
// ---------------------------------------------------------------------------
__global__ __launch_bounds__(256) void attn_kernel(const float* __restrict__ qg,
                                                   const float* __restrict__ kg,
                                                   const float* __restrict__ vg,
                                                   const int* __restrict__ mask,
                                                   float* __restrict__ ctx) {
    __shared__ __align__(16) float Qs[64][68];
    __shared__ __align__(16) float Ks[64][68];
    __shared__ __align__(16) float Vs[64][64];
    __shared__ __align__(16) float Ps[64][68];
    __shared__ int Ms[64];
    int t = threadIdx.x;
    int jt = t & 15, rt = t >> 4;      // rt 0..15
    int qb = blockIdx.x, bh = blockIdx.y;
    int b = bh / NH, h = bh - b * NH;
    size_t base = ((size_t)b * SLEN) * DM + h * DK;
    int q0 = qb * 64;

    // stage Q tile
    {
        int r = t >> 4, c4 = (t & 15) * 4;
        #pragma unroll
        for (int p = 0; p < 4; p++) {
            int rr = r + p * 16;
            *(float4*)&Qs[rr][c4] = *(const float4*)&qg[base + (size_t)(q0 + rr) * DM + c4];
        }
    }

    float mrow[4], lrow[4], O[4][4];
    #pragma unroll
    for (int ri = 0; ri < 4; ri++) {
        mrow[ri] = -INFINITY; lrow[ri] = 0.f;
        #pragma unroll
        for (int dd = 0; dd < 4; dd++) O[ri][dd] = 0.f;
    }

    for (int j0 = 0; j0 < SLEN; j0 += 64) {
        // stage K, V, mask tiles
        {
            int r = t >> 4, c4 = (t & 15) * 4;
            #pragma unroll
            for (int p = 0; p < 4; p++) {
                int rr = r + p * 16;
                *(float4*)&Ks[rr][c4] = *(const float4*)&kg[base + (size_t)(j0 + rr) * DM + c4];
                *(float4*)&Vs[rr][c4] = *(const float4*)&vg[base + (size_t)(j0 + rr) * DM + c4];
            }
            if (t < 64) Ms[t] = mask[b * SLEN + j0 + t];
        }
        __syncthreads();

        // scores: sc[ri][i] = Q[4rt+ri] . K[jt+16i]
        float sc[4][4];
        #pragma unroll
        for (int ri = 0; ri < 4; ri++)
            #pragma unroll
            for (int i = 0; i < 4; i++) sc[ri][i] = 0.f;
        for (int d = 0; d < 64; d += 4) {
            float4 q4[4], k4[4];
            #pragma unroll
            for (int ri = 0; ri < 4; ri++) q4[ri] = *(const float4*)&Qs[rt * 4 + ri][d];
            #pragma unroll
            for (int i = 0; i < 4; i++) k4[i] = *(const float4*)&Ks[jt + 16 * i][d];
            #pragma unroll
            for (int ri = 0; ri < 4; ri++)
                #pragma unroll
                for (int i = 0; i < 4; i++)
                    sc[ri][i] += q4[ri].x * k4[i].x + q4[ri].y * k4[i].y
                               + q4[ri].z * k4[i].z + q4[ri].w * k4[i].w;
        }
        #pragma unroll
        for (int i = 0; i < 4; i++) {
            int mv = Ms[jt + 16 * i];
            #pragma unroll
            for (int ri = 0; ri < 4; ri++) {
                float s = sc[ri][i] * 0.125f;       // 1/sqrt(64)
                sc[ri][i] = (mv == 0) ? -1e9f : s;
            }
        }
        // online softmax update (16 threads per row share state redundantly)
        #pragma unroll
        for (int ri = 0; ri < 4; ri++) {
            float lm = fmaxf(fmaxf(sc[ri][0], sc[ri][1]), fmaxf(sc[ri][2], sc[ri][3]));
            #pragma unroll
            for (int off = 1; off < 16; off <<= 1) lm = fmaxf(lm, __shfl_xor(lm, off));
            float mnew = fmaxf(mrow[ri], lm);
            float al = __expf(mrow[ri] - mnew);
            float ps = 0.f;
            #pragma unroll
            for (int i = 0; i < 4; i++) {
                float p = __expf(sc[ri][i] - mnew);
                sc[ri][i] = p;
                ps += p;
            }
            #pragma unroll
            for (int off = 1; off < 16; off <<= 1) ps += __shfl_xor(ps, off);
            lrow[ri] = lrow[ri] * al + ps;
            mrow[ri] = mnew;
            #pragma unroll
            for (int dd = 0; dd < 4; dd++) O[ri][dd] *= al;
        }
        // share P through LDS
        #pragma unroll
        for (int ri = 0; ri < 4; ri++)
            #pragma unroll
            for (int i = 0; i < 4; i++)
                Ps[rt * 4 + ri][jt + 16 * i] = sc[ri][i];
        __syncthreads();
        // PV: O[r][d] += sum_j P[r][j] * V[j][d]
        for (int j = 0; j < 64; j += 4) {
            float4 p4[4], v4[4];
            #pragma unroll
            for (int ri = 0; ri < 4; ri++) p4[ri] = *(const float4*)&Ps[rt * 4 + ri][j];
            #pragma unroll
            for (int jj = 0; jj < 4; jj++) v4[jj] = *(const float4*)&Vs[j + jj][jt * 4];
            #pragma unroll
            for (int ri = 0; ri < 4; ri++) {
                O[ri][0] += p4[ri].x * v4[0].x + p4[ri].y * v4[1].x + p4[ri].z * v4[2].x + p4[ri].w * v4[3].x;
                O[ri][1] += p4[ri].x * v4[0].y + p4[ri].y * v4[1].y + p4[ri].z * v4[2].y + p4[ri].w * v4[3].y;
                O[ri][2] += p4[ri].x * v4[0].z + p4[ri].y * v4[1].z + p4[ri].z * v4[2].z + p4[ri].w * v4[3].z;
                O[ri][3] += p4[ri].x * v4[0].w + p4[ri].y * v4[1].w + p4[ri].z * v4[2].w + p4[ri].w * v4[3].w;
            }
        }
        __syncthreads();
    }
    // epilogue: normalize and store
    #pragma unroll
    for (int ri = 0; ri < 4; ri++) {
        float inv = 1.0f / lrow[ri];
        float4 o;
        o.x = O[ri][0] * inv; o.y = O[ri][1] * inv;
        o.z = O[ri][2] * inv; o.w = O[ri][3] * inv;
        *(float4*)&ctx[base + (size_t)(q0 + rt * 4 + ri) * DM + jt * 4] = o;
    }
}

// ---------------------------------------------------------------------------
extern "C" void kernel_launch(void* const* d_in, const int* in_sizes, int n_in,
                              void* d_out, int out_size, void* d_ws, size_t ws_size,
                              hipStream_t stream) {
    const float* x     = (const float*)d_in[0];
    const int*   mask  = (const int*)d_in[1];
    const float* wq    = (const float*)d_in[2];
    const float* bq    = (const float*)d_in[3];
    const float* wk    = (const float*)d_in[4];
    const float* bk    = (const float*)d_in[5];
    const float* wv    = (const float*)d_in[6];
    const float* bv    = (const float*)d_in[7];
    const float* wo    = (const float*)d_in[8];
    const float* bo    = (const float*)d_in[9];
    const float* w1    = (const float*)d_in[10];
    const float* b1    = (const float*)d_in[11];
    const float* w2    = (const float*)d_in[12];
    const float* b2    = (const float*)d_in[13];
    const float* ln1a  = (const float*)d_in[14];
    const float* ln1b  = (const float*)d_in[15];
    const float* ln2a  = (const float*)d_in[16];
    const float* ln2b  = (const float*)d_in[17];
    float* out = (float*)d_out;

    const size_t MD = (size_t)MTOT * DM;   // 3,145,728 floats
    float* ws   = (float*)d_ws;
    float* h    = ws;                 // [4096,768]  LN output (reused for LN2)
    float* q    = ws + 1 * MD;        // [4096,768]
    float* k    = ws + 2 * MD;        // [4096,768]
    float* v    = ws + 3 * MD;        // [4096,768]
    float* ctx  = ws + 4 * MD;        // [4096,768]
    float* x1   = ws + 5 * MD;        // [4096,768]  residual-1 output
    float* ffn  = ws + 1 * MD;        // [4096,3072] reuses q..ctx (dead by then)

    // 1. h = LN1(x)
    ln_kernel<<<MTOT, 256, 0, stream>>>(x, h, ln1a, ln1b);
    // 2. q,k,v = h @ {wq,wk,wv} + b   (one fused launch, z selects projection)
    qkv_kernel<<<dim3(MTOT / 128, DM / 128, 3), 256, 0, stream>>>(
        h, wq, bq, wk, bk, wv, bv, q, k, v);
    // 3. ctx = flash-attention(q,k,v)
    attn_kernel<<<dim3(SLEN / 64, BATCH * NH), 256, 0, stream>>>(q, k, v, mask, ctx);
    // 4. x1 = x + ctx @ wo + bo
    sgemm_kernel<false, true><<<dim3(MTOT / 128, DM / 128), 256, 0, stream>>>(
        ctx, wo, bo, x, x1, MTOT, DM, DM);
    // 5. h = LN2(x1)
    ln_kernel<<<MTOT, 256, 0, stream>>>(x1, h, ln2a, ln2b);
    // 6. ffn = relu(h @ w1 + b1)
    sgemm_kernel<true, false><<<dim3(MTOT / 128, DFF / 128), 256, 0, stream>>>(
        h, w1, b1, nullptr, ffn, MTOT, DFF, DM);
    // 7. out = x1 + ffn @ w2 + b2
    sgemm_kernel<false, true><<<dim3(MTOT / 128, DM / 128), 256, 0, stream>>>(
        ffn, w2, b2, x1, out, MTOT, DM, DFF);
}

// Round 2
// 371.995 us; speedup vs baseline: 4.3181x; 4.3181x over previous
//
#include <hip/hip_runtime.h>
#include <math.h>

#define DM    768
#define NH    12
#define DKH   64
#define DFF   3072
#define BATCH 2
#define SLEN  2048
#define MTOT  4096
#define LNEPS 1e-6f

typedef unsigned short u16;
typedef __attribute__((ext_vector_type(8))) short bf16x8;   // 8 bf16 = 4 VGPRs (MFMA A/B frag)
typedef __attribute__((ext_vector_type(4))) float f32x4;    // MFMA C/D frag
typedef __attribute__((ext_vector_type(4))) unsigned short us4;

__device__ __forceinline__ u16 f2bf(float f) {              // RNE float->bf16
    union { float f; unsigned int u; } v; v.f = f;
    unsigned int r = v.u + 0x7FFFu + ((v.u >> 16) & 1u);
    return (u16)(r >> 16);
}

// async global->LDS, 16 B per lane. LDS dest = wave-uniform base + lane*16.
__device__ __forceinline__ void gld16(const void* g, void* lds) {
    __builtin_amdgcn_global_load_lds(
        (const __attribute__((address_space(1))) unsigned int*)(unsigned long long)g,
        (__attribute__((address_space(3))) unsigned int*)(unsigned int)(unsigned long long)lds,
        16, 0, 0);
}

// ---------------------------------------------------------------------------
// LayerNorm fp32 in -> bf16 out. One block per row, 256 threads, 3 elems each.
// ---------------------------------------------------------------------------
__global__ __launch_bounds__(256) void ln_kernel(const float* __restrict__ x,
                                                 u16* __restrict__ out,
                                                 const float* __restrict__ alpha_p,
                                                 const float* __restrict__ beta_p) {
    int row = blockIdx.x;
    const float* xr = x + (size_t)row * DM;
    int t = threadIdx.x;
    float v0 = xr[t], v1 = xr[t + 256], v2 = xr[t + 512];
    float s = v0 + v1 + v2;
    #pragma unroll
    for (int off = 32; off > 0; off >>= 1) s += __shfl_down(s, off);
    __shared__ float red[4], red2[4];
    int wv = t >> 6, ln = t & 63;
    if (ln == 0) red[wv] = s;
    __syncthreads();
    float mean = (red[0] + red[1] + red[2] + red[3]) * (1.0f / 768.0f);
    float d0 = v0 - mean, d1 = v1 - mean, d2 = v2 - mean;
    float sq = d0 * d0 + d1 * d1 + d2 * d2;
    #pragma unroll
    for (int off = 32; off > 0; off >>= 1) sq += __shfl_down(sq, off);
    if (ln == 0) red2[wv] = sq;
    __syncthreads();
    float var = (red2[0] + red2[1] + red2[2] + red2[3]) * (1.0f / 767.0f); // ddof=1
    float scale = alpha_p[0] / (sqrtf(var) + LNEPS);
    float bias = beta_p[0];
    u16* orow = out + (size_t)row * DM;
    orow[t]       = f2bf(d0 * scale + bias);
    orow[t + 256] = f2bf(d1 * scale + bias);
    orow[t + 512] = f2bf(d2 * scale + bias);
}

// ---------------------------------------------------------------------------
// Weight cast+transpose: src[R][C] fp32 -> dst[C][R] bf16. 32x32 LDS tiles.
// ---------------------------------------------------------------------------
__global__ __launch_bounds__(256) void wcast_t(const float* __restrict__ src,
                                               u16* __restrict__ dst, int R, int C) {
    __shared__ float tile[32][33];
    int t = threadIdx.x, tx = t & 31, ty = t >> 5;
    int r0 = blockIdx.y * 32, c0 = blockIdx.x * 32;
    #pragma unroll
    for (int p = 0; p < 4; p++)
        tile[ty + p * 8][tx] = src[(size_t)(r0 + ty + p * 8) * C + c0 + tx];
    __syncthreads();
    #pragma unroll
    for (int p = 0; p < 4; p++)
        dst[(size_t)(c0 + ty + p * 8) * R + r0 + tx] = f2bf(tile[tx][ty + p * 8]);
}

// ---------------------------------------------------------------------------
// bf16 MFMA GEMM: C = A[M,K] @ Wt[N,K]^T + bias (A,Wt bf16 row-major).
// 128x128 tile, 256 threads = 4 waves (2x2), each wave 64x64 = 4x4 MFMA tiles.
// BK=32, global_load_lds dwordx4 staging, 8 ds_read_b128 + 16 MFMA / wave / step.
// EPI: 0 = bf16 out, 1 = bf16 relu out, 2 = fp32 out + resid, 3 = bf16 out
//      transposed (dst[n][m], for V so attention's PV B-operand is contiguous).
// ---------------------------------------------------------------------------
template<int EPI>
__device__ __forceinline__ void gemm_core(const u16* __restrict__ A,
                                          const u16* __restrict__ Wt,
                                          const float* __restrict__ bias,
                                          const float* __restrict__ resid,
                                          void* __restrict__ Cout,
                                          int M, int N, int K, int bm, int bn) {
    __shared__ __align__(16) u16 As[128 * 32];   // [m][k], 64 B rows
    __shared__ __align__(16) u16 Bs[128 * 32];   // [n][k]
    int t = threadIdx.x;
    int ln = t & 63, w = t >> 6;
    int wm = w >> 1, wn = w & 1;
    int quad = ln >> 4, col = ln & 15;
    int m0 = bm * 128, n0 = bn * 128;

    f32x4 acc[4][4];
    const f32x4 zero = {0.f, 0.f, 0.f, 0.f};
    #pragma unroll
    for (int i = 0; i < 4; i++)
        #pragma unroll
        for (int j = 0; j < 4; j++) acc[i][j] = zero;

    // staging: wave w covers rows [32w,32w+32), 16 rows (64 B each) per inst
    const u16* Ag = A  + (size_t)(m0 + 32 * w + (ln >> 2)) * K + (ln & 3) * 8;
    const u16* Bg = Wt + (size_t)(n0 + 32 * w + (ln >> 2)) * K + (ln & 3) * 8;
    u16* Al = As + w * 1024;   // byte offset 2048*w
    u16* Bl = Bs + w * 1024;

    for (int k0 = 0; k0 < K; k0 += 32) {
        gld16(Ag + k0,              Al);
        gld16(Ag + k0 + 16 * K,     Al + 512);
        gld16(Bg + k0,              Bl);
        gld16(Bg + k0 + 16 * K,     Bl + 512);
        __syncthreads();
        bf16x8 af[4], bfr[4];
        #pragma unroll
        for (int i = 0; i < 4; i++)
            af[i] = *(const bf16x8*)&As[(wm * 64 + i * 16 + col) * 32 + quad * 8];
        #pragma unroll
        for (int j = 0; j < 4; j++)
            bfr[j] = *(const bf16x8*)&Bs[(wn * 64 + j * 16 + col) * 32 + quad * 8];
        #pragma unroll
        for (int i = 0; i < 4; i++)
            #pragma unroll
            for (int j = 0; j < 4; j++)
                acc[i][j] = __builtin_amdgcn_mfma_f32_16x16x32_bf16(af[i], bfr[j], acc[i][j], 0, 0, 0);
        __syncthreads();
    }

    // epilogue: C/D layout col = lane&15, row = quad*4 + reg
    #pragma unroll
    for (int i = 0; i < 4; i++) {
        int mb = m0 + wm * 64 + i * 16 + quad * 4;
        #pragma unroll
        for (int j = 0; j < 4; j++) {
            int n = n0 + wn * 64 + j * 16 + col;
            float bs = bias[n];
            if (EPI == 0 || EPI == 1) {
                u16* Cb = (u16*)Cout;
                #pragma unroll
                for (int r = 0; r < 4; r++) {
                    float f = acc[i][j][r] + bs;
                    if (EPI == 1) f = fmaxf(f, 0.f);
                    Cb[(size_t)(mb + r) * N + n] = f2bf(f);
                }
            } else if (EPI == 2) {
                float* Cf = (float*)Cout;
                #pragma unroll
                for (int r = 0; r < 4; r++)
                    Cf[(size_t)(mb + r) * N + n] =
                        acc[i][j][r] + bs + resid[(size_t)(mb + r) * N + n];
            } else {  // EPI == 3: transposed bf16, dst[n][m] (row stride M)
                u16* Cb = (u16*)Cout;
                us4 pk;
                #pragma unroll
                for (int r = 0; r < 4; r++) pk[r] = f2bf(acc[i][j][r] + bs);
                *(us4*)&Cb[(size_t)n * M + mb] = pk;
            }
        }
    }
}

template<int EPI>
__global__ __launch_bounds__(256) void gemm_kernel(const u16* __restrict__ A,
                                                   const u16* __restrict__ Wt,
                                                   const float* __restrict__ bias,
                                                   const float* __restrict__ resid,
                                                   void* __restrict__ C,
                                                   int M, int N, int K) {
    gemm_core<EPI>(A, Wt, bias, resid, C, M, N, K, blockIdx.x, blockIdx.y);
}

// Fused QKV: z=0 -> q (bf16 rm), z=1 -> k (bf16 rm), z=2 -> v transposed.
__global__ __launch_bounds__(256) void qkv_kernel(const u16* __restrict__ h,
        const u16* __restrict__ wqT, const u16* __restrict__ wkT, const u16* __restrict__ wvT,
        const float* __restrict__ bq, const float* __restrict__ bk, const float* __restrict__ bv,
        u16* __restrict__ q, u16* __restrict__ k, u16* __restrict__ vT) {
    int z = blockIdx.z;
    if (z == 0)      gemm_core<0>(h, wqT, bq, nullptr, q,  MTOT, DM, DM, blockIdx.x, blockIdx.y);
    else if (z == 1) gemm_core<0>(h, wkT, bk, nullptr, k,  MTOT, DM, DM, blockIdx.x, blockIdx.y);
    else             gemm_core<3>(h, wvT, bv, nullptr, vT, MTOT, DM, DM, blockIdx.x, blockIdx.y);
}

// ---------------------------------------------------------------------------
// bf16 MFMA flash attention. Block = 4 waves, BQ=64 (wave = 16 q-rows), BK=64.
// q,k row-major [4096][768] bf16 (head slice = 64-col chunk); v transposed
// vT[768][4096] bf16. Qs/Ks/Vt rows are 64 bf16 (128 B); 16 B chunks are
// XOR-swizzled (chunk ^= row&7) via the GLOBAL address so global_load_lds's
// lane-ordered LDS writes land swizzled -> conflict-free ds_read_b128.
// S exits MFMA in C-layout; P re-enters PV via LDS A-layout round-trip.
// ---------------------------------------------------------------------------
__global__ __launch_bounds__(256) void attn_kernel(const u16* __restrict__ qg,
                                                   const u16* __restrict__ kg,
                                                   const u16* __restrict__ vTg,
                                                   const int* __restrict__ mask,
                                                   u16* __restrict__ ctx) {
    __shared__ __align__(16) u16 Qs[64 * 64];
    __shared__ __align__(16) u16 Ks[64 * 64];
    __shared__ __align__(16) u16 Vt[64 * 64];        // [d][seq]
    __shared__ __align__(16) u16 Ps[4 * 16 * 64];    // per-wave 16x64
    __shared__ int Ms[64];
    int t = threadIdx.x, ln = t & 63, w = t >> 6;
    int quad = ln >> 4, col = ln & 15;
    int qb = blockIdx.x, bh = blockIdx.y;
    int b = bh / NH, h = bh - b * NH;
    int q0 = qb * 64;
    size_t qkbase = ((size_t)b * SLEN) * DM + h * DKH;
    size_t vbase  = ((size_t)h * DKH) * MTOT + (size_t)b * SLEN;

    int sw_st = (((ln & 7) ^ (ln >> 3)) * 8);        // staging-side swizzled chunk
    int c0 = ((quad ^ (ln & 7)) * 8);                // read-side: k 0..31 chunk
    int c1 = c0 ^ 32;                                //            k 32..63 chunk

    // stage Q (wave w -> rows 16w..16w+15, 8 rows per inst)
    {
        const u16* g0 = qg + qkbase + (size_t)(q0 + 16 * w + (ln >> 3)) * DM + sw_st;
        gld16(g0,          Qs + w * 1024);
        gld16(g0 + 8 * DM, Qs + w * 1024 + 512);
    }

    float mrow[4], lrow[4];
    f32x4 Ov[4];
    const f32x4 zero = {0.f, 0.f, 0.f, 0.f};
    #pragma unroll
    for (int r = 0; r < 4; r++) { mrow[r] = -INFINITY; lrow[r] = 0.f; }
    #pragma unroll
    for (int j = 0; j < 4; j++) Ov[j] = zero;

    u16* Psw = Ps + w * 1024;
    int rowQ = (w * 16 + col) * 64;

    for (int j0 = 0; j0 < SLEN; j0 += 64) {
        {
            const u16* kg0 = kg + qkbase + (size_t)(j0 + 16 * w + (ln >> 3)) * DM + sw_st;
            gld16(kg0,          Ks + w * 1024);
            gld16(kg0 + 8 * DM, Ks + w * 1024 + 512);
            const u16* vg0 = vTg + vbase + (size_t)(16 * w + (ln >> 3)) * MTOT + j0 + sw_st;
            gld16(vg0,             Vt + w * 1024);
            gld16(vg0 + 8 * MTOT,  Vt + w * 1024 + 512);
            if (t < 64) Ms[t] = mask[b * SLEN + j0 + t];
        }
        __syncthreads();

        // --- S = Q K^T (per wave: 16 q-rows x 64 keys)
        f32x4 S[4];
        bf16x8 aq0 = *(const bf16x8*)&Qs[rowQ + c0];
        bf16x8 aq1 = *(const bf16x8*)&Qs[rowQ + c1];
        #pragma unroll
        for (int j = 0; j < 4; j++) {
            int rk = (j * 16 + col) * 64;
            bf16x8 b0 = *(const bf16x8*)&Ks[rk + c0];
            bf16x8 b1 = *(const bf16x8*)&Ks[rk + c1];
            f32x4 s = __builtin_amdgcn_mfma_f32_16x16x32_bf16(aq0, b0, zero, 0, 0, 0);
            S[j]     = __builtin_amdgcn_mfma_f32_16x16x32_bf16(aq1, b1, s,    0, 0, 0);
        }
        // --- scale + mask
        #pragma unroll
        for (int j = 0; j < 4; j++) {
            int mv = Ms[j * 16 + col];
            #pragma unroll
            for (int r = 0; r < 4; r++) {
                float sv = S[j][r] * 0.125f;   // 1/sqrt(64)
                S[j][r] = (mv == 0) ? -1e9f : sv;
            }
        }
        // --- online softmax (rows = quad*4+r, replicated over 16 lanes)
        float alpha[4];
        #pragma unroll
        for (int r = 0; r < 4; r++) {
            float rm = fmaxf(fmaxf(S[0][r], S[1][r]), fmaxf(S[2][r], S[3][r]));
            #pragma unroll
            for (int off = 1; off < 16; off <<= 1) rm = fmaxf(rm, __shfl_xor(rm, off));
            float mnew = fmaxf(mrow[r], rm);
            float al = __expf(mrow[r] - mnew);
            mrow[r] = mnew;
            float ps = 0.f;
            #pragma unroll
            for (int j = 0; j < 4; j++) {
                float p = __expf(S[j][r] - mnew);
                S[j][r] = p;
                ps += p;
            }
            #pragma unroll
            for (int off = 1; off < 16; off <<= 1) ps += __shfl_xor(ps, off);
            lrow[r] = lrow[r] * al + ps;
            alpha[r] = al;
        }
        // --- P: C-layout regs -> LDS (bf16), O rescale
        #pragma unroll
        for (int j = 0; j < 4; j++)
            #pragma unroll
            for (int r = 0; r < 4; r++)
                Psw[(quad * 4 + r) * 64 + j * 16 + col] = f2bf(S[j][r]);
        #pragma unroll
        for (int j = 0; j < 4; j++)
            #pragma unroll
            for (int r = 0; r < 4; r++) Ov[j][r] *= alpha[r];
        // --- O += P V (A-frag from Psw, B-frag from Vt)
        bf16x8 ap0 = *(const bf16x8*)&Psw[col * 64 + quad * 8];
        bf16x8 ap1 = *(const bf16x8*)&Psw[col * 64 + 32 + quad * 8];
        #pragma unroll
        for (int j = 0; j < 4; j++) {
            int rv = (j * 16 + col) * 64;
            bf16x8 b0 = *(const bf16x8*)&Vt[rv + c0];
            bf16x8 b1 = *(const bf16x8*)&Vt[rv + c1];
            Ov[j] = __builtin_amdgcn_mfma_f32_16x16x32_bf16(ap0, b0, Ov[j], 0, 0, 0);
            Ov[j] = __builtin_amdgcn_mfma_f32_16x16x32_bf16(ap1, b1, Ov[j], 0, 0, 0);
        }
        __syncthreads();
    }
    // epilogue: ctx bf16 row-major [4096][768]
    float inv[4];
    #pragma unroll
    for (int r = 0; r < 4; r++) inv[r] = 1.0f / lrow[r];
    #pragma unroll
    for (int j = 0; j < 4; j++)
        #pragma unroll
        for (int r = 0; r < 4; r++)
            ctx[qkbase + (size_t)(q0 + w * 16 + quad * 4 + r) * DM + j * 16 + col] =
                f2bf(Ov[j][r] * inv[r]);
}

// ---------------------------------------------------------------------------
extern "C" void kernel_launch(void* const* d_in, const int* in_sizes, int n_in,
                              void* d_out, int out_size, void* d_ws, size_t ws_size,
                              hipStream_t stream) {
    const float* x    = (const float*)d_in[0];
    const int*   mask = (const int*)d_in[1];
    const float* wq   = (const float*)d_in[2];
    const float* bq   = (const float*)d_in[3];
    const float* wk   = (const float*)d_in[4];
    const float* bk   = (const float*)d_in[5];
    const float* wv   = (const float*)d_in[6];
    const float* bv   = (const float*)d_in[7];
    const float* wo   = (const float*)d_in[8];
    const float* bo   = (const float*)d_in[9];
    const float* w1   = (const float*)d_in[10];
    const float* b1   = (const float*)d_in[11];
    const float* w2   = (const float*)d_in[12];
    const float* b2   = (const float*)d_in[13];
    const float* ln1a = (const float*)d_in[14];
    const float* ln1b = (const float*)d_in[15];
    const float* ln2a = (const float*)d_in[16];
    const float* ln2b = (const float*)d_in[17];
    float* out = (float*)d_out;

    // workspace layout (bytes); ffn overlays q/k/vT/ctx (dead by FFN1)
    char* w8 = (char*)d_ws;
    u16*   ffn = (u16*)(w8 + 0);          // [4096][3072] bf16 = 25,165,824 B
    u16*   q   = (u16*)(w8 + 0);          // [4096][768] bf16
    u16*   kb  = (u16*)(w8 + 6291456);
    u16*   vT  = (u16*)(w8 + 12582912);   // [768][4096] bf16
    u16*   ctx = (u16*)(w8 + 18874368);
    u16*   h   = (u16*)(w8 + 25165824);   // [4096][768] bf16
    float* x1  = (float*)(w8 + 31457280); // [4096][768] fp32
    u16*   wqT = (u16*)(w8 + 44040192);
    u16*   wkT = (u16*)(w8 + 45219840);
    u16*   wvT = (u16*)(w8 + 46399488);
    u16*   woT = (u16*)(w8 + 47579136);
    u16*   w1T = (u16*)(w8 + 48758784);   // [3072][768]
    u16*   w2T = (u16*)(w8 + 53477376);   // [768][3072]

    // 0. weights -> bf16 transposed (Wt[n][k])
    wcast_t<<<dim3(24, 24), 256, 0, stream>>>(wq, wqT, DM, DM);
    wcast_t<<<dim3(24, 24), 256, 0, stream>>>(wk, wkT, DM, DM);
    wcast_t<<<dim3(24, 24), 256, 0, stream>>>(wv, wvT, DM, DM);
    wcast_t<<<dim3(24, 24), 256, 0, stream>>>(wo, woT, DM, DM);
    wcast_t<<<dim3(96, 24), 256, 0, stream>>>(w1, w1T, DM, DFF);
    wcast_t<<<dim3(24, 96), 256, 0, stream>>>(w2, w2T, DFF, DM);
    // 1. h = LN1(x)
    ln_kernel<<<MTOT, 256, 0, stream>>>(x, h, ln1a, ln1b);
    // 2. q,k row-major; v transposed
    qkv_kernel<<<dim3(32, 6, 3), 256, 0, stream>>>(h, wqT, wkT, wvT, bq, bk, bv, q, kb, vT);
    // 3. ctx = flash-attention(q,k,vT)
    attn_kernel<<<dim3(SLEN / 64, BATCH * NH), 256, 0, stream>>>(q, kb, vT, mask, ctx);
    // 4. x1 = x + ctx @ wo + bo   (fp32 out)
    gemm_kernel<2><<<dim3(32, 6), 256, 0, stream>>>(ctx, woT, bo, x, (void*)x1, MTOT, DM, DM);
    // 5. h = LN2(x1)
    ln_kernel<<<MTOT, 256, 0, stream>>>(x1, h, ln2a, ln2b);
    // 6. ffn = relu(h @ w1 + b1)  (bf16)
    gemm_kernel<1><<<dim3(32, 24), 256, 0, stream>>>(h, w1T, b1, nullptr, (void*)ffn, MTOT, DFF, DM);
    // 7. out = x1 + ffn @ w2 + b2 (fp32)
    gemm_kernel<2><<<dim3(32, 6), 256, 0, stream>>>(ffn, w2T, b2, x1, (void*)out, MTOT, DM, DFF);
}

// Round 3
// 336.623 us; speedup vs baseline: 4.7718x; 1.1051x over previous
//
#include <hip/hip_runtime.h>
#include <math.h>

#define DM    768
#define NH    12
#define DKH   64
#define DFF   3072
#define BATCH 2
#define SLEN  2048
#define MTOT  4096
#define LNEPS 1e-6f
#define QSCALE 0.18033688011112042f   // 0.125 * log2(e): softmax in exp2 domain

typedef unsigned short u16;
typedef __attribute__((ext_vector_type(8))) short bf16x8;   // MFMA A/B frag (4 VGPRs)
typedef __attribute__((ext_vector_type(4))) float f32x4;    // MFMA C/D frag
typedef __attribute__((ext_vector_type(4))) unsigned short us4;

__device__ __forceinline__ u16 f2bf(float f) {              // RNE float->bf16
    union { float f; unsigned int u; } v; v.f = f;
    unsigned int r = v.u + 0x7FFFu + ((v.u >> 16) & 1u);
    return (u16)(r >> 16);
}

// async global->LDS, 16 B per lane. LDS dest = wave-uniform base + lane*16.
__device__ __forceinline__ void gld16(const void* g, void* lds) {
    __builtin_amdgcn_global_load_lds(
        (const __attribute__((address_space(1))) unsigned int*)(unsigned long long)g,
        (__attribute__((address_space(3))) unsigned int*)(unsigned int)(unsigned long long)lds,
        16, 0, 0);
}

// ---------------------------------------------------------------------------
// LayerNorm fp32 in -> bf16 out. One block per row, 256 threads, 3 elems each.
// ---------------------------------------------------------------------------
__global__ __launch_bounds__(256) void ln_kernel(const float* __restrict__ x,
                                                 u16* __restrict__ out,
                                                 const float* __restrict__ alpha_p,
                                                 const float* __restrict__ beta_p) {
    int row = blockIdx.x;
    const float* xr = x + (size_t)row * DM;
    int t = threadIdx.x;
    float v0 = xr[t], v1 = xr[t + 256], v2 = xr[t + 512];
    float s = v0 + v1 + v2;
    #pragma unroll
    for (int off = 32; off > 0; off >>= 1) s += __shfl_down(s, off);
    __shared__ float red[4], red2[4];
    int wv = t >> 6, ln = t & 63;
    if (ln == 0) red[wv] = s;
    __syncthreads();
    float mean = (red[0] + red[1] + red[2] + red[3]) * (1.0f / 768.0f);
    float d0 = v0 - mean, d1 = v1 - mean, d2 = v2 - mean;
    float sq = d0 * d0 + d1 * d1 + d2 * d2;
    #pragma unroll
    for (int off = 32; off > 0; off >>= 1) sq += __shfl_down(sq, off);
    if (ln == 0) red2[wv] = sq;
    __syncthreads();
    float var = (red2[0] + red2[1] + red2[2] + red2[3]) * (1.0f / 767.0f); // ddof=1
    float scale = alpha_p[0] / (sqrtf(var) + LNEPS);
    float bias = beta_p[0];
    u16* orow = out + (size_t)row * DM;
    orow[t]       = f2bf(d0 * scale + bias);
    orow[t + 256] = f2bf(d1 * scale + bias);
    orow[t + 512] = f2bf(d2 * scale + bias);
}

// ---------------------------------------------------------------------------
// Weight cast+transpose: src[R][C] fp32 -> dst[C][R] bf16. 32x32 LDS tiles.
// ---------------------------------------------------------------------------
__global__ __launch_bounds__(256) void wcast_t(const float* __restrict__ src,
                                               u16* __restrict__ dst, int R, int C) {
    __shared__ float tile[32][33];
    int t = threadIdx.x, tx = t & 31, ty = t >> 5;
    int r0 = blockIdx.y * 32, c0 = blockIdx.x * 32;
    #pragma unroll
    for (int p = 0; p < 4; p++)
        tile[ty + p * 8][tx] = src[(size_t)(r0 + ty + p * 8) * C + c0 + tx];
    __syncthreads();
    #pragma unroll
    for (int p = 0; p < 4; p++)
        dst[(size_t)(c0 + ty + p * 8) * R + r0 + tx] = f2bf(tile[tx][ty + p * 8]);
}

// ---------------------------------------------------------------------------
// bf16 MFMA GEMM core, 128x128 tile, BK=32, double-buffered staging (one
// barrier per K-step, prefetch issued before compute). 4 waves (2x2), each
// wave 64x64 = 4x4 MFMA 16x16x32 tiles.
// EPI: 0 = bf16 out *scale, 1 = bf16 relu, 2 = fp32 + resid,
//      3 = bf16 transposed (dst[n][m]), 5 = fp32 atomicAdd (split-K)
// ---------------------------------------------------------------------------
template<int EPI>
__device__ __forceinline__ void gemm128_core(const u16* __restrict__ A,
                                             const u16* __restrict__ Wt,
                                             const float* __restrict__ bias,
                                             const float* __restrict__ resid,
                                             void* __restrict__ Cout,
                                             int M, int N, int Kstride, int Kloop,
                                             float scale, int bm, int bn) {
    __shared__ __align__(16) u16 As[2][128 * 32];
    __shared__ __align__(16) u16 Bs[2][128 * 32];
    int t = threadIdx.x;
    int ln = t & 63, w = t >> 6;
    int wm = w >> 1, wn = w & 1;
    int quad = ln >> 4, col = ln & 15;
    int m0 = bm * 128, n0 = bn * 128;

    f32x4 acc[4][4];
    const f32x4 zero = {0.f, 0.f, 0.f, 0.f};
    #pragma unroll
    for (int i = 0; i < 4; i++)
        #pragma unroll
        for (int j = 0; j < 4; j++) acc[i][j] = zero;

    const u16* Ag = A  + (size_t)(m0 + 32 * w + (ln >> 2)) * Kstride + (ln & 3) * 8;
    const u16* Bg = Wt + (size_t)(n0 + 32 * w + (ln >> 2)) * Kstride + (ln & 3) * 8;

    gld16(Ag,                As[0] + w * 1024);
    gld16(Ag + 16 * Kstride, As[0] + w * 1024 + 512);
    gld16(Bg,                Bs[0] + w * 1024);
    gld16(Bg + 16 * Kstride, Bs[0] + w * 1024 + 512);
    __syncthreads();

    for (int k0 = 0; k0 < Kloop; k0 += 32) {
        int cur = (k0 >> 5) & 1, nxt = cur ^ 1;
        if (k0 + 32 < Kloop) {      // prefetch next slab before compute
            gld16(Ag + k0 + 32,                As[nxt] + w * 1024);
            gld16(Ag + k0 + 32 + 16 * Kstride, As[nxt] + w * 1024 + 512);
            gld16(Bg + k0 + 32,                Bs[nxt] + w * 1024);
            gld16(Bg + k0 + 32 + 16 * Kstride, Bs[nxt] + w * 1024 + 512);
        }
        bf16x8 af[4], bfr[4];
        #pragma unroll
        for (int i = 0; i < 4; i++)
            af[i] = *(const bf16x8*)&As[cur][(wm * 64 + i * 16 + col) * 32 + quad * 8];
        #pragma unroll
        for (int j = 0; j < 4; j++)
            bfr[j] = *(const bf16x8*)&Bs[cur][(wn * 64 + j * 16 + col) * 32 + quad * 8];
        #pragma unroll
        for (int i = 0; i < 4; i++)
            #pragma unroll
            for (int j = 0; j < 4; j++)
                acc[i][j] = __builtin_amdgcn_mfma_f32_16x16x32_bf16(af[i], bfr[j], acc[i][j], 0, 0, 0);
        __syncthreads();
    }

    // epilogue: C/D layout col = lane&15, row = quad*4 + reg
    #pragma unroll
    for (int i = 0; i < 4; i++) {
        int mb = m0 + wm * 64 + i * 16 + quad * 4;
        #pragma unroll
        for (int j = 0; j < 4; j++) {
            int n = n0 + wn * 64 + j * 16 + col;
            if (EPI == 0 || EPI == 1) {
                float bs = bias[n];
                u16* Cb = (u16*)Cout;
                #pragma unroll
                for (int r = 0; r < 4; r++) {
                    float f = (acc[i][j][r] + bs) * ((EPI == 0) ? scale : 1.0f);
                    if (EPI == 1) f = fmaxf(f, 0.f);
                    Cb[(size_t)(mb + r) * N + n] = f2bf(f);
                }
            } else if (EPI == 2) {
                float bs = bias[n];
                float* Cf = (float*)Cout;
                #pragma unroll
                for (int r = 0; r < 4; r++)
                    Cf[(size_t)(mb + r) * N + n] =
                        acc[i][j][r] + bs + resid[(size_t)(mb + r) * N + n];
            } else if (EPI == 3) {  // transposed bf16, dst[n][m]
                float bs = bias[n];
                u16* Cb = (u16*)Cout;
                us4 pk;
                #pragma unroll
                for (int r = 0; r < 4; r++) pk[r] = f2bf(acc[i][j][r] + bs);
                *(us4*)&Cb[(size_t)n * M + mb] = pk;
            } else {                // EPI == 5: split-K atomic accumulate
                float* Cf = (float*)Cout;
                #pragma unroll
                for (int r = 0; r < 4; r++)
                    atomicAdd(&Cf[(size_t)(mb + r) * N + n], acc[i][j][r]);
            }
        }
    }
}

template<int EPI>
__global__ __launch_bounds__(256) void gemm_kernel(const u16* __restrict__ A,
                                                   const u16* __restrict__ Wt,
                                                   const float* __restrict__ bias,
                                                   const float* __restrict__ resid,
                                                   void* __restrict__ C,
                                                   int M, int N, int Kstride, int Kloop,
                                                   float scale) {
    const u16* Az = A  + (size_t)blockIdx.z * Kloop;   // split-K offset (z=0 if unsplit)
    const u16* Wz = Wt + (size_t)blockIdx.z * Kloop;
    gemm128_core<EPI>(Az, Wz, bias, resid, C, M, N, Kstride, Kloop, scale,
                      blockIdx.y, blockIdx.x);
}

// Fused QKV: z=0 -> q (bf16, pre-scaled by 0.125*log2e), z=1 -> k, z=2 -> vT.
__global__ __launch_bounds__(256) void qkv_kernel(const u16* __restrict__ h,
        const u16* __restrict__ wqT, const u16* __restrict__ wkT, const u16* __restrict__ wvT,
        const float* __restrict__ bq, const float* __restrict__ bk, const float* __restrict__ bv,
        u16* __restrict__ q, u16* __restrict__ k, u16* __restrict__ vT) {
    int z = blockIdx.z;
    if (z == 0)      gemm128_core<0>(h, wqT, bq, nullptr, q,  MTOT, DM, DM, DM, QSCALE, blockIdx.y, blockIdx.x);
    else if (z == 1) gemm128_core<0>(h, wkT, bk, nullptr, k,  MTOT, DM, DM, DM, 1.0f,   blockIdx.y, blockIdx.x);
    else             gemm128_core<3>(h, wvT, bv, nullptr, vT, MTOT, DM, DM, DM, 1.0f,   blockIdx.y, blockIdx.x);
}

// ---------------------------------------------------------------------------
// 64x64-tile GEMM (for narrow/latency-bound Wo): 4 waves 2x2, 32x32/wave,
// double-buffered. EPI=2 (fp32 + resid) only path used.
// ---------------------------------------------------------------------------
template<int EPI>
__global__ __launch_bounds__(256) void gemm64_kernel(const u16* __restrict__ A,
                                                     const u16* __restrict__ Wt,
                                                     const float* __restrict__ bias,
                                                     const float* __restrict__ resid,
                                                     void* __restrict__ Cout,
                                                     int M, int N, int Kstride, int Kloop) {
    __shared__ __align__(16) u16 As[2][64 * 32];
    __shared__ __align__(16) u16 Bs[2][64 * 32];
    int t = threadIdx.x, ln = t & 63, w = t >> 6;
    int wm = w >> 1, wn = w & 1;
    int quad = ln >> 4, col = ln & 15;
    int m0 = blockIdx.y * 64, n0 = blockIdx.x * 64;

    f32x4 acc[2][2];
    const f32x4 zero = {0.f, 0.f, 0.f, 0.f};
    #pragma unroll
    for (int i = 0; i < 2; i++)
        #pragma unroll
        for (int j = 0; j < 2; j++) acc[i][j] = zero;

    const u16* Ag = A  + (size_t)(m0 + 16 * w + (ln >> 2)) * Kstride + (ln & 3) * 8;
    const u16* Bg = Wt + (size_t)(n0 + 16 * w + (ln >> 2)) * Kstride + (ln & 3) * 8;
    gld16(Ag, As[0] + w * 512);
    gld16(Bg, Bs[0] + w * 512);
    __syncthreads();

    for (int k0 = 0; k0 < Kloop; k0 += 32) {
        int cur = (k0 >> 5) & 1, nxt = cur ^ 1;
        if (k0 + 32 < Kloop) {
            gld16(Ag + k0 + 32, As[nxt] + w * 512);
            gld16(Bg + k0 + 32, Bs[nxt] + w * 512);
        }
        bf16x8 af[2], bfr[2];
        #pragma unroll
        for (int i = 0; i < 2; i++)
            af[i] = *(const bf16x8*)&As[cur][(wm * 32 + i * 16 + col) * 32 + quad * 8];
        #pragma unroll
        for (int j = 0; j < 2; j++)
            bfr[j] = *(const bf16x8*)&Bs[cur][(wn * 32 + j * 16 + col) * 32 + quad * 8];
        #pragma unroll
        for (int i = 0; i < 2; i++)
            #pragma unroll
            for (int j = 0; j < 2; j++)
                acc[i][j] = __builtin_amdgcn_mfma_f32_16x16x32_bf16(af[i], bfr[j], acc[i][j], 0, 0, 0);
        __syncthreads();
    }

    #pragma unroll
    for (int i = 0; i < 2; i++) {
        int mb = m0 + wm * 32 + i * 16 + quad * 4;
        #pragma unroll
        for (int j = 0; j < 2; j++) {
            int n = n0 + wn * 32 + j * 16 + col;
            float bs = bias[n];
            float* Cf = (float*)Cout;
            #pragma unroll
            for (int r = 0; r < 4; r++)
                Cf[(size_t)(mb + r) * N + n] =
                    acc[i][j][r] + bs + resid[(size_t)(mb + r) * N + n];
        }
    }
}

// out = x1 + b2 (broadcast), fp32. Basis for FFN2's split-K atomic adds.
__global__ __launch_bounds__(256) void init_out(const float* __restrict__ x1,
                                                const float* __restrict__ b2,
                                                float* __restrict__ out) {
    int e = (blockIdx.x * 256 + threadIdx.x) * 4;
    float4 xv = *(const float4*)&x1[e];
    float4 bv = *(const float4*)&b2[e % DM];
    float4 o;
    o.x = xv.x + bv.x; o.y = xv.y + bv.y; o.z = xv.z + bv.z; o.w = xv.w + bv.w;
    *(float4*)&out[e] = o;
}

// ---------------------------------------------------------------------------
// bf16 MFMA flash attention, S^T formulation. Block = 4 waves, BQ=64
// (wave = 16 q-rows), BK=64, K/V double-buffered (one barrier per tile).
// S^T = K·Q^T so softmax state is per-col(q) [2-shuffle reductions] and P
// exits in a layout writable as contiguous ds_write_b64 into stride-72 Ps
// (write & read both bank-conflict-free). Q frags hoisted; scores arrive in
// exp2 domain (Q pre-scaled). Grid (bh, qb) => same-bh blocks share an XCD.
// ---------------------------------------------------------------------------
__global__ __launch_bounds__(256) void attn_kernel(const u16* __restrict__ qg,
                                                   const u16* __restrict__ kg,
                                                   const u16* __restrict__ vTg,
                                                   const int* __restrict__ mask,
                                                   u16* __restrict__ ctx) {
    __shared__ __align__(16) u16 Qs[64 * 64];
    __shared__ __align__(16) u16 Ks[2][64 * 64];
    __shared__ __align__(16) u16 Vt[2][64 * 64];     // [d][seq]
    __shared__ __align__(16) u16 Ps[4][16 * 72];     // per-wave, padded stride 72
    __shared__ int Ms[2][64];
    int t = threadIdx.x, ln = t & 63, w = t >> 6;
    int quad = ln >> 4, col = ln & 15;
    int bh = blockIdx.x, qb = blockIdx.y;
    int b = bh / NH, h = bh - b * NH;
    int q0 = qb * 64;
    size_t qkbase = ((size_t)b * SLEN) * DM + h * DKH;
    size_t vbase  = ((size_t)h * DKH) * MTOT + (size_t)b * SLEN;

    int sw_st = (((ln & 7) ^ (ln >> 3)) * 8);        // staging-side swizzled chunk
    int c0 = ((quad ^ (ln & 7)) * 8);                // read-side: k 0..31 chunk
    int c1 = c0 ^ 32;                                //            k 32..63 chunk

    // stage Q + K/V tile 0 + mask 0
    {
        const u16* g0 = qg + qkbase + (size_t)(q0 + 16 * w + (ln >> 3)) * DM + sw_st;
        gld16(g0,          Qs + w * 1024);
        gld16(g0 + 8 * DM, Qs + w * 1024 + 512);
        const u16* kg0 = kg + qkbase + (size_t)(16 * w + (ln >> 3)) * DM + sw_st;
        gld16(kg0,          Ks[0] + w * 1024);
        gld16(kg0 + 8 * DM, Ks[0] + w * 1024 + 512);
        const u16* vg0 = vTg + vbase + (size_t)(16 * w + (ln >> 3)) * MTOT + sw_st;
        gld16(vg0,            Vt[0] + w * 1024);
        gld16(vg0 + 8 * MTOT, Vt[0] + w * 1024 + 512);
        if (t < 64) Ms[0][t] = mask[b * SLEN + t];
    }
    __syncthreads();

    // hoisted Q B-frags (Qs is never rewritten)
    int rowQ = (w * 16 + col) * 64;
    bf16x8 bq0 = *(const bf16x8*)&Qs[rowQ + c0];
    bf16x8 bq1 = *(const bf16x8*)&Qs[rowQ + c1];

    float mrow = -INFINITY, lrow = 0.f;              // state for q = col
    f32x4 Ov[4];
    const f32x4 zero = {0.f, 0.f, 0.f, 0.f};
    #pragma unroll
    for (int j = 0; j < 4; j++) Ov[j] = zero;
    u16* Psw = &Ps[w][0];

    for (int j0 = 0; j0 < SLEN; j0 += 64) {
        int cur = (j0 >> 6) & 1, nxt = cur ^ 1;
        if (j0 + 64 < SLEN) {                        // prefetch next K/V tile
            const u16* kg0 = kg + qkbase + (size_t)(j0 + 64 + 16 * w + (ln >> 3)) * DM + sw_st;
            gld16(kg0,          Ks[nxt] + w * 1024);
            gld16(kg0 + 8 * DM, Ks[nxt] + w * 1024 + 512);
            const u16* vg0 = vTg + vbase + (size_t)(16 * w + (ln >> 3)) * MTOT + j0 + 64 + sw_st;
            gld16(vg0,            Vt[nxt] + w * 1024);
            gld16(vg0 + 8 * MTOT, Vt[nxt] + w * 1024 + 512);
            if (t < 64) Ms[nxt][t] = mask[b * SLEN + j0 + 64 + t];
        }

        // --- S^T = K·Q^T: tile j rows = keys j*16+quad*4+r, cols = q
        f32x4 S[4];
        #pragma unroll
        for (int j = 0; j < 4; j++) {
            int rk = (j * 16 + col) * 64;
            bf16x8 ak0 = *(const bf16x8*)&Ks[cur][rk + c0];
            bf16x8 ak1 = *(const bf16x8*)&Ks[cur][rk + c1];
            f32x4 s = __builtin_amdgcn_mfma_f32_16x16x32_bf16(ak0, bq0, zero, 0, 0, 0);
            S[j]     = __builtin_amdgcn_mfma_f32_16x16x32_bf16(ak1, bq1, s,    0, 0, 0);
        }
        // --- mask (per key = row)
        #pragma unroll
        for (int j = 0; j < 4; j++) {
            int m4[4];
            *(int4*)m4 = *(const int4*)&Ms[cur][j * 16 + quad * 4];
            #pragma unroll
            for (int r = 0; r < 4; r++)
                S[j][r] = (m4[r] == 0) ? -1e9f : S[j][r];
        }
        // --- online softmax over keys (local 16 + xor16 + xor32)
        float lm = S[0][0];
        #pragma unroll
        for (int j = 0; j < 4; j++)
            #pragma unroll
            for (int r = 0; r < 4; r++) lm = fmaxf(lm, S[j][r]);
        lm = fmaxf(lm, __shfl_xor(lm, 16));
        lm = fmaxf(lm, __shfl_xor(lm, 32));
        float mnew = fmaxf(mrow, lm);
        float al = exp2f(mrow - mnew);
        float ps = 0.f;
        #pragma unroll
        for (int j = 0; j < 4; j++)
            #pragma unroll
            for (int r = 0; r < 4; r++) {
                float p = exp2f(S[j][r] - mnew);
                S[j][r] = p;
                ps += p;
            }
        ps += __shfl_xor(ps, 16);
        ps += __shfl_xor(ps, 32);
        lrow = lrow * al + ps;
        mrow = mnew;
        // --- P write: rows = q = col, keys contiguous along r -> ds_write_b64
        #pragma unroll
        for (int j = 0; j < 4; j++) {
            us4 pk;
            #pragma unroll
            for (int r = 0; r < 4; r++) pk[r] = f2bf(S[j][r]);
            *(us4*)&Psw[col * 72 + j * 16 + quad * 4] = pk;
        }
        // --- rescale Ov (alpha indexed by q-row = quad*4+r, fetched by shfl)
        float alr[4];
        #pragma unroll
        for (int r = 0; r < 4; r++) alr[r] = __shfl(al, quad * 4 + r);
        #pragma unroll
        for (int j = 0; j < 4; j++)
            #pragma unroll
            for (int r = 0; r < 4; r++) Ov[j][r] *= alr[r];
        // --- O += P·V
        bf16x8 ap0 = *(const bf16x8*)&Psw[col * 72 + quad * 8];
        bf16x8 ap1 = *(const bf16x8*)&Psw[col * 72 + 32 + quad * 8];
        #pragma unroll
        for (int j = 0; j < 4; j++) {
            int rv = (j * 16 + col) * 64;
            bf16x8 bv0 = *(const bf16x8*)&Vt[cur][rv + c0];
            bf16x8 bv1 = *(const bf16x8*)&Vt[cur][rv + c1];
            Ov[j] = __builtin_amdgcn_mfma_f32_16x16x32_bf16(ap0, bv0, Ov[j], 0, 0, 0);
            Ov[j] = __builtin_amdgcn_mfma_f32_16x16x32_bf16(ap1, bv1, Ov[j], 0, 0, 0);
        }
        __syncthreads();   // waves done with cur; nxt loads drained (vmcnt0)
    }
    // epilogue: O rows = q = quad*4+r, cols = d = j*16+col
    float linv = 1.0f / lrow;
    float invr[4];
    #pragma unroll
    for (int r = 0; r < 4; r++) invr[r] = __shfl(linv, quad * 4 + r);
    #pragma unroll
    for (int j = 0; j < 4; j++)
        #pragma unroll
        for (int r = 0; r < 4; r++)
            ctx[qkbase + (size_t)(q0 + w * 16 + quad * 4 + r) * DM + j * 16 + col] =
                f2bf(Ov[j][r] * invr[r]);
}

// ---------------------------------------------------------------------------
extern "C" void kernel_launch(void* const* d_in, const int* in_sizes, int n_in,
                              void* d_out, int out_size, void* d_ws, size_t ws_size,
                              hipStream_t stream) {
    const float* x    = (const float*)d_in[0];
    const int*   mask = (const int*)d_in[1];
    const float* wq   = (const float*)d_in[2];
    const float* bq   = (const float*)d_in[3];
    const float* wk   = (const float*)d_in[4];
    const float* bk   = (const float*)d_in[5];
    const float* wv   = (const float*)d_in[6];
    const float* bv   = (const float*)d_in[7];
    const float* wo   = (const float*)d_in[8];
    const float* bo   = (const float*)d_in[9];
    const float* w1   = (const float*)d_in[10];
    const float* b1   = (const float*)d_in[11];
    const float* w2   = (const float*)d_in[12];
    const float* b2   = (const float*)d_in[13];
    const float* ln1a = (const float*)d_in[14];
    const float* ln1b = (const float*)d_in[15];
    const float* ln2a = (const float*)d_in[16];
    const float* ln2b = (const float*)d_in[17];
    float* out = (float*)d_out;

    // workspace layout (bytes); ffn overlays q/k/vT/ctx (dead by FFN1)
    char* w8 = (char*)d_ws;
    u16*   ffn = (u16*)(w8 + 0);          // [4096][3072] bf16
    u16*   q   = (u16*)(w8 + 0);          // [4096][768] bf16 (pre-scaled)
    u16*   kb  = (u16*)(w8 + 6291456);
    u16*   vT  = (u16*)(w8 + 12582912);   // [768][4096] bf16
    u16*   ctx = (u16*)(w8 + 18874368);
    u16*   h   = (u16*)(w8 + 25165824);   // [4096][768] bf16
    float* x1  = (float*)(w8 + 31457280); // [4096][768] fp32
    u16*   wqT = (u16*)(w8 + 44040192);
    u16*   wkT = (u16*)(w8 + 45219840);
    u16*   wvT = (u16*)(w8 + 46399488);
    u16*   woT = (u16*)(w8 + 47579136);
    u16*   w1T = (u16*)(w8 + 48758784);   // [3072][768]
    u16*   w2T = (u16*)(w8 + 53477376);   // [768][3072]

    // 0. weights -> bf16 transposed (Wt[n][k])
    wcast_t<<<dim3(24, 24), 256, 0, stream>>>(wq, wqT, DM, DM);
    wcast_t<<<dim3(24, 24), 256, 0, stream>>>(wk, wkT, DM, DM);
    wcast_t<<<dim3(24, 24), 256, 0, stream>>>(wv, wvT, DM, DM);
    wcast_t<<<dim3(24, 24), 256, 0, stream>>>(wo, woT, DM, DM);
    wcast_t<<<dim3(96, 24), 256, 0, stream>>>(w1, w1T, DM, DFF);
    wcast_t<<<dim3(24, 96), 256, 0, stream>>>(w2, w2T, DFF, DM);
    // 1. h = LN1(x)
    ln_kernel<<<MTOT, 256, 0, stream>>>(x, h, ln1a, ln1b);
    // 2. q (pre-scaled), k row-major; v transposed. grid (n,m,proj)
    qkv_kernel<<<dim3(6, 32, 3), 256, 0, stream>>>(h, wqT, wkT, wvT, bq, bk, bv, q, kb, vT);
    // 3. ctx = flash-attention; grid (bh, qb) for XCD K/V locality
    attn_kernel<<<dim3(BATCH * NH, SLEN / 64), 256, 0, stream>>>(q, kb, vT, mask, ctx);
    // 4. x1 = x + ctx @ wo + bo  (64x64 tiles: 768 blocks vs 192)
    gemm64_kernel<2><<<dim3(12, 64), 256, 0, stream>>>(ctx, woT, bo, x, (void*)x1,
                                                       MTOT, DM, DM, DM);
    // 5. h = LN2(x1)
    ln_kernel<<<MTOT, 256, 0, stream>>>(x1, h, ln2a, ln2b);
    // 6. ffn = relu(h @ w1 + b1)
    gemm_kernel<1><<<dim3(24, 32), 256, 0, stream>>>(h, w1T, b1, nullptr, (void*)ffn,
                                                     MTOT, DFF, DM, DM, 1.0f);
    // 7. out = x1 + b2; then split-K=2 atomic accumulate of ffn @ w2
    init_out<<<MTOT * DM / 1024, 256, 0, stream>>>(x1, b2, out);
    gemm_kernel<5><<<dim3(6, 32, 2), 256, 0, stream>>>(ffn, w2T, nullptr, nullptr, (void*)out,
                                                       MTOT, DM, DFF, DFF / 2, 1.0f);
}

// Round 4
// 310.461 us; speedup vs baseline: 5.1740x; 1.0843x over previous
//
#include <hip/hip_runtime.h>
#include <math.h>

#define DM    768
#define NH    12
#define DKH   64
#define DFF   3072
#define BATCH 2
#define SLEN  2048
#define MTOT  4096
#define LNEPS 1e-6f
#define QSCALE 0.18033688011112042f   // 0.125 * log2(e): softmax in exp2 domain

typedef unsigned short u16;
typedef __attribute__((ext_vector_type(8))) short bf16x8;   // MFMA A/B frag (4 VGPRs)
typedef __attribute__((ext_vector_type(4))) float f32x4;    // MFMA C/D frag
typedef __attribute__((ext_vector_type(4))) unsigned short us4;

__device__ __forceinline__ u16 f2bf(float f) {              // RNE float->bf16
    union { float f; unsigned int u; } v; v.f = f;
    unsigned int r = v.u + 0x7FFFu + ((v.u >> 16) & 1u);
    return (u16)(r >> 16);
}

// pack two floats -> two bf16 in one u32 via v_perm_b32 (round-half-up)
__device__ __forceinline__ unsigned pk2bf(float lo, float hi) {
    union { float f; unsigned u; } a, b;
    a.f = lo; b.f = hi;
    return __builtin_amdgcn_perm(b.u + 0x8000u, a.u + 0x8000u, 0x07060302u);
}

// async global->LDS, 16 B per lane. LDS dest = wave-uniform base + lane*16.
__device__ __forceinline__ void gld16(const void* g, void* lds) {
    __builtin_amdgcn_global_load_lds(
        (const __attribute__((address_space(1))) unsigned int*)(unsigned long long)g,
        (__attribute__((address_space(3))) unsigned int*)(unsigned int)(unsigned long long)lds,
        16, 0, 0);
}

// ---------------------------------------------------------------------------
// LayerNorm fp32 in -> bf16 out. One block per row, 256 threads, 3 elems each.
// ---------------------------------------------------------------------------
__global__ __launch_bounds__(256) void ln_kernel(const float* __restrict__ x,
                                                 u16* __restrict__ out,
                                                 const float* __restrict__ alpha_p,
                                                 const float* __restrict__ beta_p) {
    int row = blockIdx.x;
    const float* xr = x + (size_t)row * DM;
    int t = threadIdx.x;
    float v0 = xr[t], v1 = xr[t + 256], v2 = xr[t + 512];
    float s = v0 + v1 + v2;
    #pragma unroll
    for (int off = 32; off > 0; off >>= 1) s += __shfl_down(s, off);
    __shared__ float red[4], red2[4];
    int wv = t >> 6, ln = t & 63;
    if (ln == 0) red[wv] = s;
    __syncthreads();
    float mean = (red[0] + red[1] + red[2] + red[3]) * (1.0f / 768.0f);
    float d0 = v0 - mean, d1 = v1 - mean, d2 = v2 - mean;
    float sq = d0 * d0 + d1 * d1 + d2 * d2;
    #pragma unroll
    for (int off = 32; off > 0; off >>= 1) sq += __shfl_down(sq, off);
    if (ln == 0) red2[wv] = sq;
    __syncthreads();
    float var = (red2[0] + red2[1] + red2[2] + red2[3]) * (1.0f / 767.0f); // ddof=1
    float scale = alpha_p[0] / (sqrtf(var) + LNEPS);
    float bias = beta_p[0];
    u16* orow = out + (size_t)row * DM;
    orow[t]       = f2bf(d0 * scale + bias);
    orow[t + 256] = f2bf(d1 * scale + bias);
    orow[t + 512] = f2bf(d2 * scale + bias);
}

// ---------------------------------------------------------------------------
// Fused weight cast+transpose: all six weights in ONE launch (6912 tiles).
// src[R][C] fp32 -> dst[C][R] bf16, 32x32 LDS tiles.
// ---------------------------------------------------------------------------
__global__ __launch_bounds__(256) void wcast_all(
        const float* __restrict__ wq, const float* __restrict__ wk,
        const float* __restrict__ wv, const float* __restrict__ wo,
        const float* __restrict__ w1, const float* __restrict__ w2,
        u16* __restrict__ wqT, u16* __restrict__ wkT, u16* __restrict__ wvT,
        u16* __restrict__ woT, u16* __restrict__ w1T, u16* __restrict__ w2T) {
    __shared__ float tile[32][33];
    int bid = blockIdx.x;
    const float* src; u16* dst; int R, C, bx, by;
    if (bid < 2304) {
        int j = bid / 576, tix = bid % 576;
        R = 768; C = 768; bx = tix % 24; by = tix / 24;
        src = (j == 0) ? wq : (j == 1) ? wk : (j == 2) ? wv : wo;
        dst = (j == 0) ? wqT : (j == 1) ? wkT : (j == 2) ? wvT : woT;
    } else if (bid < 4608) {
        int tix = bid - 2304;
        R = 768; C = 3072; bx = tix % 96; by = tix / 96;
        src = w1; dst = w1T;
    } else {
        int tix = bid - 4608;
        R = 3072; C = 768; bx = tix % 24; by = tix / 24;
        src = w2; dst = w2T;
    }
    int t = threadIdx.x, tx = t & 31, ty = t >> 5;
    int r0 = by * 32, c0 = bx * 32;
    #pragma unroll
    for (int p = 0; p < 4; p++)
        tile[ty + p * 8][tx] = src[(size_t)(r0 + ty + p * 8) * C + c0 + tx];
    __syncthreads();
    #pragma unroll
    for (int p = 0; p < 4; p++)
        dst[(size_t)(c0 + ty + p * 8) * R + r0 + tx] = f2bf(tile[tx][ty + p * 8]);
}

// ---------------------------------------------------------------------------
// bf16 MFMA GEMM core, 128x128 tile, BK=32, double-buffered staging (one
// barrier per K-step). 4 waves (2x2), each wave 64x64 = 4x4 MFMA tiles.
// EPI: 0 = bf16 out *scale, 1 = bf16 relu, 2 = fp32 + resid,
//      3 = bf16 transposed (dst[n][m]), 5 = fp32 atomicAdd (split-K)
// ---------------------------------------------------------------------------
template<int EPI>
__device__ __forceinline__ void gemm128_core(const u16* __restrict__ A,
                                             const u16* __restrict__ Wt,
                                             const float* __restrict__ bias,
                                             const float* __restrict__ resid,
                                             void* __restrict__ Cout,
                                             int M, int N, int Kstride, int Kloop,
                                             float scale, int bm, int bn) {
    __shared__ __align__(16) u16 As[2][128 * 32];
    __shared__ __align__(16) u16 Bs[2][128 * 32];
    int t = threadIdx.x;
    int ln = t & 63, w = t >> 6;
    int wm = w >> 1, wn = w & 1;
    int quad = ln >> 4, col = ln & 15;
    int m0 = bm * 128, n0 = bn * 128;

    f32x4 acc[4][4];
    const f32x4 zero = {0.f, 0.f, 0.f, 0.f};
    #pragma unroll
    for (int i = 0; i < 4; i++)
        #pragma unroll
        for (int j = 0; j < 4; j++) acc[i][j] = zero;

    const u16* Ag = A  + (size_t)(m0 + 32 * w + (ln >> 2)) * Kstride + (ln & 3) * 8;
    const u16* Bg = Wt + (size_t)(n0 + 32 * w + (ln >> 2)) * Kstride + (ln & 3) * 8;

    gld16(Ag,                As[0] + w * 1024);
    gld16(Ag + 16 * Kstride, As[0] + w * 1024 + 512);
    gld16(Bg,                Bs[0] + w * 1024);
    gld16(Bg + 16 * Kstride, Bs[0] + w * 1024 + 512);
    __syncthreads();

    for (int k0 = 0; k0 < Kloop; k0 += 32) {
        int cur = (k0 >> 5) & 1, nxt = cur ^ 1;
        if (k0 + 32 < Kloop) {      // prefetch next slab before compute
            gld16(Ag + k0 + 32,                As[nxt] + w * 1024);
            gld16(Ag + k0 + 32 + 16 * Kstride, As[nxt] + w * 1024 + 512);
            gld16(Bg + k0 + 32,                Bs[nxt] + w * 1024);
            gld16(Bg + k0 + 32 + 16 * Kstride, Bs[nxt] + w * 1024 + 512);
        }
        bf16x8 af[4], bfr[4];
        #pragma unroll
        for (int i = 0; i < 4; i++)
            af[i] = *(const bf16x8*)&As[cur][(wm * 64 + i * 16 + col) * 32 + quad * 8];
        #pragma unroll
        for (int j = 0; j < 4; j++)
            bfr[j] = *(const bf16x8*)&Bs[cur][(wn * 64 + j * 16 + col) * 32 + quad * 8];
        #pragma unroll
        for (int i = 0; i < 4; i++)
            #pragma unroll
            for (int j = 0; j < 4; j++)
                acc[i][j] = __builtin_amdgcn_mfma_f32_16x16x32_bf16(af[i], bfr[j], acc[i][j], 0, 0, 0);
        __syncthreads();
    }

    // epilogue: C/D layout col = lane&15, row = quad*4 + reg
    #pragma unroll
    for (int i = 0; i < 4; i++) {
        int mb = m0 + wm * 64 + i * 16 + quad * 4;
        #pragma unroll
        for (int j = 0; j < 4; j++) {
            int n = n0 + wn * 64 + j * 16 + col;
            if (EPI == 0 || EPI == 1) {
                float bs = bias[n];
                u16* Cb = (u16*)Cout;
                #pragma unroll
                for (int r = 0; r < 4; r++) {
                    float f = (acc[i][j][r] + bs) * ((EPI == 0) ? scale : 1.0f);
                    if (EPI == 1) f = fmaxf(f, 0.f);
                    Cb[(size_t)(mb + r) * N + n] = f2bf(f);
                }
            } else if (EPI == 2) {
                float bs = bias[n];
                float* Cf = (float*)Cout;
                #pragma unroll
                for (int r = 0; r < 4; r++)
                    Cf[(size_t)(mb + r) * N + n] =
                        acc[i][j][r] + bs + resid[(size_t)(mb + r) * N + n];
            } else if (EPI == 3) {  // transposed bf16, dst[n][m]
                float bs = bias[n];
                u16* Cb = (u16*)Cout;
                us4 pk;
                #pragma unroll
                for (int r = 0; r < 4; r++) pk[r] = f2bf(acc[i][j][r] + bs);
                *(us4*)&Cb[(size_t)n * M + mb] = pk;
            } else {                // EPI == 5: split-K atomic accumulate
                float* Cf = (float*)Cout;
                #pragma unroll
                for (int r = 0; r < 4; r++)
                    atomicAdd(&Cf[(size_t)(mb + r) * N + n], acc[i][j][r]);
            }
        }
    }
}

template<int EPI>
__global__ __launch_bounds__(256) void gemm_kernel(const u16* __restrict__ A,
                                                   const u16* __restrict__ Wt,
                                                   const float* __restrict__ bias,
                                                   const float* __restrict__ resid,
                                                   void* __restrict__ C,
                                                   int M, int N, int Kstride, int Kloop,
                                                   float scale) {
    const u16* Az = A  + (size_t)blockIdx.z * Kloop;   // split-K offset (z=0 if unsplit)
    const u16* Wz = Wt + (size_t)blockIdx.z * Kloop;
    gemm128_core<EPI>(Az, Wz, bias, resid, C, M, N, Kstride, Kloop, scale,
                      blockIdx.y, blockIdx.x);
}

// Fused QKV: z=0 -> q (bf16, pre-scaled by 0.125*log2e), z=1 -> k, z=2 -> vT.
__global__ __launch_bounds__(256) void qkv_kernel(const u16* __restrict__ h,
        const u16* __restrict__ wqT, const u16* __restrict__ wkT, const u16* __restrict__ wvT,
        const float* __restrict__ bq, const float* __restrict__ bk, const float* __restrict__ bv,
        u16* __restrict__ q, u16* __restrict__ k, u16* __restrict__ vT) {
    int z = blockIdx.z;
    if (z == 0)      gemm128_core<0>(h, wqT, bq, nullptr, q,  MTOT, DM, DM, DM, QSCALE, blockIdx.y, blockIdx.x);
    else if (z == 1) gemm128_core<0>(h, wkT, bk, nullptr, k,  MTOT, DM, DM, DM, 1.0f,   blockIdx.y, blockIdx.x);
    else             gemm128_core<3>(h, wvT, bv, nullptr, vT, MTOT, DM, DM, DM, 1.0f,   blockIdx.y, blockIdx.x);
}

// ---------------------------------------------------------------------------
// 64x64-tile GEMM (for narrow/latency-bound Wo): 4 waves 2x2, 32x32/wave,
// double-buffered. EPI=2 (fp32 + resid) path.
// ---------------------------------------------------------------------------
template<int EPI>
__global__ __launch_bounds__(256) void gemm64_kernel(const u16* __restrict__ A,
                                                     const u16* __restrict__ Wt,
                                                     const float* __restrict__ bias,
                                                     const float* __restrict__ resid,
                                                     void* __restrict__ Cout,
                                                     int M, int N, int Kstride, int Kloop) {
    __shared__ __align__(16) u16 As[2][64 * 32];
    __shared__ __align__(16) u16 Bs[2][64 * 32];
    int t = threadIdx.x, ln = t & 63, w = t >> 6;
    int wm = w >> 1, wn = w & 1;
    int quad = ln >> 4, col = ln & 15;
    int m0 = blockIdx.y * 64, n0 = blockIdx.x * 64;

    f32x4 acc[2][2];
    const f32x4 zero = {0.f, 0.f, 0.f, 0.f};
    #pragma unroll
    for (int i = 0; i < 2; i++)
        #pragma unroll
        for (int j = 0; j < 2; j++) acc[i][j] = zero;

    const u16* Ag = A  + (size_t)(m0 + 16 * w + (ln >> 2)) * Kstride + (ln & 3) * 8;
    const u16* Bg = Wt + (size_t)(n0 + 16 * w + (ln >> 2)) * Kstride + (ln & 3) * 8;
    gld16(Ag, As[0] + w * 512);
    gld16(Bg, Bs[0] + w * 512);
    __syncthreads();

    for (int k0 = 0; k0 < Kloop; k0 += 32) {
        int cur = (k0 >> 5) & 1, nxt = cur ^ 1;
        if (k0 + 32 < Kloop) {
            gld16(Ag + k0 + 32, As[nxt] + w * 512);
            gld16(Bg + k0 + 32, Bs[nxt] + w * 512);
        }
        bf16x8 af[2], bfr[2];
        #pragma unroll
        for (int i = 0; i < 2; i++)
            af[i] = *(const bf16x8*)&As[cur][(wm * 32 + i * 16 + col) * 32 + quad * 8];
        #pragma unroll
        for (int j = 0; j < 2; j++)
            bfr[j] = *(const bf16x8*)&Bs[cur][(wn * 32 + j * 16 + col) * 32 + quad * 8];
        #pragma unroll
        for (int i = 0; i < 2; i++)
            #pragma unroll
            for (int j = 0; j < 2; j++)
                acc[i][j] = __builtin_amdgcn_mfma_f32_16x16x32_bf16(af[i], bfr[j], acc[i][j], 0, 0, 0);
        __syncthreads();
    }

    #pragma unroll
    for (int i = 0; i < 2; i++) {
        int mb = m0 + wm * 32 + i * 16 + quad * 4;
        #pragma unroll
        for (int j = 0; j < 2; j++) {
            int n = n0 + wn * 32 + j * 16 + col;
            float bs = bias[n];
            float* Cf = (float*)Cout;
            #pragma unroll
            for (int r = 0; r < 4; r++)
                Cf[(size_t)(mb + r) * N + n] =
                    acc[i][j][r] + bs + resid[(size_t)(mb + r) * N + n];
        }
    }
}

// out = x1 + b2 (broadcast), fp32. Basis for FFN2's split-K atomic adds.
__global__ __launch_bounds__(256) void init_out(const float* __restrict__ x1,
                                                const float* __restrict__ b2,
                                                float* __restrict__ out) {
    int e = (blockIdx.x * 256 + threadIdx.x) * 4;
    float4 xv = *(const float4*)&x1[e];
    float4 bv = *(const float4*)&b2[e % DM];
    float4 o;
    o.x = xv.x + bv.x; o.y = xv.y + bv.y; o.z = xv.z + bv.z; o.w = xv.w + bv.w;
    *(float4*)&out[e] = o;
}

// ---------------------------------------------------------------------------
// bf16 MFMA flash attention, S^T formulation, FIXED-MAX softmax.
// Scores are in exp2 domain (Q pre-scaled by 0.125*log2e) and bounded (~|6|),
// so softmax needs no running max: p = exp2(s), l = sum(p). This removes the
// max chain, alpha rescale and per-tile reductions (l reduced once at end).
// Block = 4 waves, BQ=64 (wave = 16 q-cols of S^T), BK=64, K/V double-buffered.
// P packs via v_perm (2 f32 -> u32) into stride-72 LDS, conflict-free.
// ---------------------------------------------------------------------------
__global__ __launch_bounds__(256) void attn_kernel(const u16* __restrict__ qg,
                                                   const u16* __restrict__ kg,
                                                   const u16* __restrict__ vTg,
                                                   const int* __restrict__ mask,
                                                   u16* __restrict__ ctx) {
    __shared__ __align__(16) u16 Qs[64 * 64];
    __shared__ __align__(16) u16 Ks[2][64 * 64];
    __shared__ __align__(16) u16 Vt[2][64 * 64];     // [d][seq]
    __shared__ __align__(16) u16 Ps[4][16 * 72];     // per-wave, padded stride 72
    __shared__ int Ms[2][64];
    int t = threadIdx.x, ln = t & 63, w = t >> 6;
    int quad = ln >> 4, col = ln & 15;
    int bh = blockIdx.x, qb = blockIdx.y;
    int b = bh / NH, h = bh - b * NH;
    int q0 = qb * 64;
    size_t qkbase = ((size_t)b * SLEN) * DM + h * DKH;
    size_t vbase  = ((size_t)h * DKH) * MTOT + (size_t)b * SLEN;

    int sw_st = (((ln & 7) ^ (ln >> 3)) * 8);        // staging-side swizzled chunk
    int c0 = ((quad ^ (ln & 7)) * 8);                // read-side: k 0..31 chunk
    int c1 = c0 ^ 32;                                //            k 32..63 chunk

    // stage Q + K/V tile 0 + mask 0
    {
        const u16* g0 = qg + qkbase + (size_t)(q0 + 16 * w + (ln >> 3)) * DM + sw_st;
        gld16(g0,          Qs + w * 1024);
        gld16(g0 + 8 * DM, Qs + w * 1024 + 512);
        const u16* kg0 = kg + qkbase + (size_t)(16 * w + (ln >> 3)) * DM + sw_st;
        gld16(kg0,          Ks[0] + w * 1024);
        gld16(kg0 + 8 * DM, Ks[0] + w * 1024 + 512);
        const u16* vg0 = vTg + vbase + (size_t)(16 * w + (ln >> 3)) * MTOT + sw_st;
        gld16(vg0,            Vt[0] + w * 1024);
        gld16(vg0 + 8 * MTOT, Vt[0] + w * 1024 + 512);
        if (t < 64) Ms[0][t] = mask[b * SLEN + t];
    }
    __syncthreads();

    // hoisted Q B-frags (Qs is never rewritten)
    int rowQ = (w * 16 + col) * 64;
    bf16x8 bq0 = *(const bf16x8*)&Qs[rowQ + c0];
    bf16x8 bq1 = *(const bf16x8*)&Qs[rowQ + c1];

    // loop-carried prefetch pointers (next K/V tile)
    const u16* kpn = kg + qkbase + (size_t)(64 + 16 * w + (ln >> 3)) * DM + sw_st;
    const u16* vpn = vTg + vbase + (size_t)(16 * w + (ln >> 3)) * MTOT + 64 + sw_st;
    const int* mpn = mask + b * SLEN + 64 + t;

    float lacc = 0.f;                                // per-lane partial sum of p (q=col)
    f32x4 Ov[4];
    const f32x4 zero = {0.f, 0.f, 0.f, 0.f};
    #pragma unroll
    for (int j = 0; j < 4; j++) Ov[j] = zero;
    u16* Psw = &Ps[w][0];

    for (int j0 = 0; j0 < SLEN; j0 += 64) {
        int cur = (j0 >> 6) & 1, nxt = cur ^ 1;
        if (j0 + 64 < SLEN) {                        // prefetch next K/V tile
            gld16(kpn,          Ks[nxt] + w * 1024);
            gld16(kpn + 8 * DM, Ks[nxt] + w * 1024 + 512);
            gld16(vpn,            Vt[nxt] + w * 1024);
            gld16(vpn + 8 * MTOT, Vt[nxt] + w * 1024 + 512);
            if (t < 64) Ms[nxt][t] = *mpn;
            kpn += 64 * DM; vpn += 64; mpn += 64;
        }

        // --- S^T = K·Q^T: tile j rows = keys j*16+quad*4+r, cols = q
        f32x4 S[4];
        #pragma unroll
        for (int j = 0; j < 4; j++) {
            int rk = (j * 16 + col) * 64;
            bf16x8 ak0 = *(const bf16x8*)&Ks[cur][rk + c0];
            bf16x8 ak1 = *(const bf16x8*)&Ks[cur][rk + c1];
            f32x4 s = __builtin_amdgcn_mfma_f32_16x16x32_bf16(ak0, bq0, zero, 0, 0, 0);
            S[j]     = __builtin_amdgcn_mfma_f32_16x16x32_bf16(ak1, bq1, s,    0, 0, 0);
        }
        // --- mask (per key = row), exp2, accumulate l, pack P (v_perm)
        #pragma unroll
        for (int j = 0; j < 4; j++) {
            int m4[4];
            *(int4*)m4 = *(const int4*)&Ms[cur][j * 16 + quad * 4];
            float p0 = exp2f((m4[0] == 0) ? -1e9f : S[j][0]);
            float p1 = exp2f((m4[1] == 0) ? -1e9f : S[j][1]);
            float p2 = exp2f((m4[2] == 0) ? -1e9f : S[j][2]);
            float p3 = exp2f((m4[3] == 0) ? -1e9f : S[j][3]);
            lacc += (p0 + p1) + (p2 + p3);
            uint2 pk;
            pk.x = pk2bf(p0, p1);
            pk.y = pk2bf(p2, p3);
            *(uint2*)&Psw[col * 72 + j * 16 + quad * 4] = pk;
        }
        // --- O += P·V
        bf16x8 ap0 = *(const bf16x8*)&Psw[col * 72 + quad * 8];
        bf16x8 ap1 = *(const bf16x8*)&Psw[col * 72 + 32 + quad * 8];
        #pragma unroll
        for (int j = 0; j < 4; j++) {
            int rv = (j * 16 + col) * 64;
            bf16x8 bv0 = *(const bf16x8*)&Vt[cur][rv + c0];
            bf16x8 bv1 = *(const bf16x8*)&Vt[cur][rv + c1];
            Ov[j] = __builtin_amdgcn_mfma_f32_16x16x32_bf16(ap0, bv0, Ov[j], 0, 0, 0);
            Ov[j] = __builtin_amdgcn_mfma_f32_16x16x32_bf16(ap1, bv1, Ov[j], 0, 0, 0);
        }
        __syncthreads();   // waves done with cur; nxt loads drained (vmcnt0)
    }
    // one-time l reduction across quads (keys), then normalize + store
    lacc += __shfl_xor(lacc, 16);
    lacc += __shfl_xor(lacc, 32);
    float linv = 1.0f / lacc;
    float invr[4];
    #pragma unroll
    for (int r = 0; r < 4; r++) invr[r] = __shfl(linv, quad * 4 + r);
    #pragma unroll
    for (int j = 0; j < 4; j++)
        #pragma unroll
        for (int r = 0; r < 4; r++)
            ctx[qkbase + (size_t)(q0 + w * 16 + quad * 4 + r) * DM + j * 16 + col] =
                f2bf(Ov[j][r] * invr[r]);
}

// ---------------------------------------------------------------------------
extern "C" void kernel_launch(void* const* d_in, const int* in_sizes, int n_in,
                              void* d_out, int out_size, void* d_ws, size_t ws_size,
                              hipStream_t stream) {
    const float* x    = (const float*)d_in[0];
    const int*   mask = (const int*)d_in[1];
    const float* wq   = (const float*)d_in[2];
    const float* bq   = (const float*)d_in[3];
    const float* wk   = (const float*)d_in[4];
    const float* bk   = (const float*)d_in[5];
    const float* wv   = (const float*)d_in[6];
    const float* bv   = (const float*)d_in[7];
    const float* wo   = (const float*)d_in[8];
    const float* bo   = (const float*)d_in[9];
    const float* w1   = (const float*)d_in[10];
    const float* b1   = (const float*)d_in[11];
    const float* w2   = (const float*)d_in[12];
    const float* b2   = (const float*)d_in[13];
    const float* ln1a = (const float*)d_in[14];
    const float* ln1b = (const float*)d_in[15];
    const float* ln2a = (const float*)d_in[16];
    const float* ln2b = (const float*)d_in[17];
    float* out = (float*)d_out;

    // workspace layout (bytes); ffn overlays q/k/vT/ctx (dead by FFN1)
    char* w8 = (char*)d_ws;
    u16*   ffn = (u16*)(w8 + 0);          // [4096][3072] bf16
    u16*   q   = (u16*)(w8 + 0);          // [4096][768] bf16 (pre-scaled)
    u16*   kb  = (u16*)(w8 + 6291456);
    u16*   vT  = (u16*)(w8 + 12582912);   // [768][4096] bf16
    u16*   ctx = (u16*)(w8 + 18874368);
    u16*   h   = (u16*)(w8 + 25165824);   // [4096][768] bf16
    float* x1  = (float*)(w8 + 31457280); // [4096][768] fp32
    u16*   wqT = (u16*)(w8 + 44040192);
    u16*   wkT = (u16*)(w8 + 45219840);
    u16*   wvT = (u16*)(w8 + 46399488);
    u16*   woT = (u16*)(w8 + 47579136);
    u16*   w1T = (u16*)(w8 + 48758784);   // [3072][768]
    u16*   w2T = (u16*)(w8 + 53477376);   // [768][3072]

    // 0. all weights -> bf16 transposed, single launch
    wcast_all<<<6912, 256, 0, stream>>>(wq, wk, wv, wo, w1, w2,
                                        wqT, wkT, wvT, woT, w1T, w2T);
    // 1. h = LN1(x)
    ln_kernel<<<MTOT, 256, 0, stream>>>(x, h, ln1a, ln1b);
    // 2. q (pre-scaled), k row-major; v transposed. grid (n,m,proj)
    qkv_kernel<<<dim3(6, 32, 3), 256, 0, stream>>>(h, wqT, wkT, wvT, bq, bk, bv, q, kb, vT);
    // 3. ctx = flash-attention; grid (bh, qb) for XCD K/V locality
    attn_kernel<<<dim3(BATCH * NH, SLEN / 64), 256, 0, stream>>>(q, kb, vT, mask, ctx);
    // 4. x1 = x + ctx @ wo + bo  (64x64 tiles: 768 blocks)
    gemm64_kernel<2><<<dim3(12, 64), 256, 0, stream>>>(ctx, woT, bo, x, (void*)x1,
                                                       MTOT, DM, DM, DM);
    // 5. h = LN2(x1)
    ln_kernel<<<MTOT, 256, 0, stream>>>(x1, h, ln2a, ln2b);
    // 6. ffn = relu(h @ w1 + b1)
    gemm_kernel<1><<<dim3(24, 32), 256, 0, stream>>>(h, w1T, b1, nullptr, (void*)ffn,
                                                     MTOT, DFF, DM, DM, 1.0f);
    // 7. out = x1 + b2; then split-K=2 atomic accumulate of ffn @ w2
    init_out<<<MTOT * DM / 1024, 256, 0, stream>>>(x1, b2, out);
    gemm_kernel<5><<<dim3(6, 32, 2), 256, 0, stream>>>(ffn, w2T, nullptr, nullptr, (void*)out,
                                                       MTOT, DM, DFF, DFF / 2, 1.0f);
}

// Round 5
// 295.064 us; speedup vs baseline: 5.4439x; 1.0522x over previous
//
#include <hip/hip_runtime.h>
#include <math.h>

#define DM    768
#define NH    12
#define DKH   64
#define DFF   3072
#define BATCH 2
#define SLEN  2048
#define MTOT  4096
#define LNEPS 1e-6f
#define QSCALE 0.18033688011112042f   // 0.125 * log2(e): softmax in exp2 domain

typedef unsigned short u16;
typedef __attribute__((ext_vector_type(8))) short bf16x8;   // MFMA A/B frag (4 VGPRs)
typedef __attribute__((ext_vector_type(4))) float f32x4;    // MFMA C/D frag
typedef __attribute__((ext_vector_type(4))) unsigned short us4;

__device__ __forceinline__ u16 f2bf(float f) {              // RNE float->bf16
    union { float f; unsigned int u; } v; v.f = f;
    unsigned int r = v.u + 0x7FFFu + ((v.u >> 16) & 1u);
    return (u16)(r >> 16);
}

// pack two floats -> two bf16 (TRUNCATED) in one u32 via v_perm_b32
__device__ __forceinline__ unsigned pk2bf_t(float lo, float hi) {
    union { float f; unsigned u; } a, b;
    a.f = lo; b.f = hi;
    return __builtin_amdgcn_perm(b.u, a.u, 0x07060302u);
}

// async global->LDS, 16 B per lane. LDS dest = wave-uniform base + lane*16.
__device__ __forceinline__ void gld16(const void* g, void* lds) {
    __builtin_amdgcn_global_load_lds(
        (const __attribute__((address_space(1))) unsigned int*)(unsigned long long)g,
        (__attribute__((address_space(3))) unsigned int*)(unsigned int)(unsigned long long)lds,
        16, 0, 0);
}

// ---------------------------------------------------------------------------
// LayerNorm fp32 in -> bf16 out. One block per row, 256 threads, 3 elems each.
// Optional fused epilogue (LN2): out2[row] = x[row] + b2 (fp32) — replaces the
// separate init_out kernel that seeded FFN2's split-K atomic accumulation.
// ---------------------------------------------------------------------------
__global__ __launch_bounds__(256) void ln_kernel(const float* __restrict__ x,
                                                 u16* __restrict__ out,
                                                 const float* __restrict__ alpha_p,
                                                 const float* __restrict__ beta_p,
                                                 const float* __restrict__ b2,
                                                 float* __restrict__ out2) {
    int row = blockIdx.x;
    const float* xr = x + (size_t)row * DM;
    int t = threadIdx.x;
    float v0 = xr[t], v1 = xr[t + 256], v2 = xr[t + 512];
    float s = v0 + v1 + v2;
    #pragma unroll
    for (int off = 32; off > 0; off >>= 1) s += __shfl_down(s, off);
    __shared__ float red[4], red2[4];
    int wv = t >> 6, ln = t & 63;
    if (ln == 0) red[wv] = s;
    __syncthreads();
    float mean = (red[0] + red[1] + red[2] + red[3]) * (1.0f / 768.0f);
    float d0 = v0 - mean, d1 = v1 - mean, d2 = v2 - mean;
    float sq = d0 * d0 + d1 * d1 + d2 * d2;
    #pragma unroll
    for (int off = 32; off > 0; off >>= 1) sq += __shfl_down(sq, off);
    if (ln == 0) red2[wv] = sq;
    __syncthreads();
    float var = (red2[0] + red2[1] + red2[2] + red2[3]) * (1.0f / 767.0f); // ddof=1
    float scale = alpha_p[0] / (sqrtf(var) + LNEPS);
    float bias = beta_p[0];
    u16* orow = out + (size_t)row * DM;
    orow[t]       = f2bf(d0 * scale + bias);
    orow[t + 256] = f2bf(d1 * scale + bias);
    orow[t + 512] = f2bf(d2 * scale + bias);
    if (out2) {
        float* o2 = out2 + (size_t)row * DM;
        o2[t]       = v0 + b2[t];
        o2[t + 256] = v1 + b2[t + 256];
        o2[t + 512] = v2 + b2[t + 512];
    }
}

// ---------------------------------------------------------------------------
// Fused weight cast+transpose: all six weights in ONE launch (6912 tiles).
// ---------------------------------------------------------------------------
__global__ __launch_bounds__(256) void wcast_all(
        const float* __restrict__ wq, const float* __restrict__ wk,
        const float* __restrict__ wv, const float* __restrict__ wo,
        const float* __restrict__ w1, const float* __restrict__ w2,
        u16* __restrict__ wqT, u16* __restrict__ wkT, u16* __restrict__ wvT,
        u16* __restrict__ woT, u16* __restrict__ w1T, u16* __restrict__ w2T) {
    __shared__ float tile[32][33];
    int bid = blockIdx.x;
    const float* src; u16* dst; int R, C, bx, by;
    if (bid < 2304) {
        int j = bid / 576, tix = bid % 576;
        R = 768; C = 768; bx = tix % 24; by = tix / 24;
        src = (j == 0) ? wq : (j == 1) ? wk : (j == 2) ? wv : wo;
        dst = (j == 0) ? wqT : (j == 1) ? wkT : (j == 2) ? wvT : woT;
    } else if (bid < 4608) {
        int tix = bid - 2304;
        R = 768; C = 3072; bx = tix % 96; by = tix / 96;
        src = w1; dst = w1T;
    } else {
        int tix = bid - 4608;
        R = 3072; C = 768; bx = tix % 24; by = tix / 24;
        src = w2; dst = w2T;
    }
    int t = threadIdx.x, tx = t & 31, ty = t >> 5;
    int r0 = by * 32, c0 = bx * 32;
    #pragma unroll
    for (int p = 0; p < 4; p++)
        tile[ty + p * 8][tx] = src[(size_t)(r0 + ty + p * 8) * C + c0 + tx];
    __syncthreads();
    #pragma unroll
    for (int p = 0; p < 4; p++)
        dst[(size_t)(c0 + ty + p * 8) * R + r0 + tx] = f2bf(tile[tx][ty + p * 8]);
}

// ---------------------------------------------------------------------------
// bf16 MFMA GEMM core, 128x128 tile, BK=32, double-buffered staging.
// EPI: 0 = bf16 out *scale, 1 = bf16 relu, 2 = fp32 + resid,
//      3 = bf16 transposed (dst[n][m]), 5 = fp32 atomicAdd (split-K)
// ---------------------------------------------------------------------------
template<int EPI>
__device__ __forceinline__ void gemm128_core(const u16* __restrict__ A,
                                             const u16* __restrict__ Wt,
                                             const float* __restrict__ bias,
                                             const float* __restrict__ resid,
                                             void* __restrict__ Cout,
                                             int M, int N, int Kstride, int Kloop,
                                             float scale, int bm, int bn) {
    __shared__ __align__(16) u16 As[2][128 * 32];
    __shared__ __align__(16) u16 Bs[2][128 * 32];
    int t = threadIdx.x;
    int ln = t & 63, w = t >> 6;
    int wm = w >> 1, wn = w & 1;
    int quad = ln >> 4, col = ln & 15;
    int m0 = bm * 128, n0 = bn * 128;

    f32x4 acc[4][4];
    const f32x4 zero = {0.f, 0.f, 0.f, 0.f};
    #pragma unroll
    for (int i = 0; i < 4; i++)
        #pragma unroll
        for (int j = 0; j < 4; j++) acc[i][j] = zero;

    const u16* Ag = A  + (size_t)(m0 + 32 * w + (ln >> 2)) * Kstride + (ln & 3) * 8;
    const u16* Bg = Wt + (size_t)(n0 + 32 * w + (ln >> 2)) * Kstride + (ln & 3) * 8;

    gld16(Ag,                As[0] + w * 1024);
    gld16(Ag + 16 * Kstride, As[0] + w * 1024 + 512);
    gld16(Bg,                Bs[0] + w * 1024);
    gld16(Bg + 16 * Kstride, Bs[0] + w * 1024 + 512);
    __syncthreads();

    for (int k0 = 0; k0 < Kloop; k0 += 32) {
        int cur = (k0 >> 5) & 1, nxt = cur ^ 1;
        if (k0 + 32 < Kloop) {
            gld16(Ag + k0 + 32,                As[nxt] + w * 1024);
            gld16(Ag + k0 + 32 + 16 * Kstride, As[nxt] + w * 1024 + 512);
            gld16(Bg + k0 + 32,                Bs[nxt] + w * 1024);
            gld16(Bg + k0 + 32 + 16 * Kstride, Bs[nxt] + w * 1024 + 512);
        }
        bf16x8 af[4], bfr[4];
        #pragma unroll
        for (int i = 0; i < 4; i++)
            af[i] = *(const bf16x8*)&As[cur][(wm * 64 + i * 16 + col) * 32 + quad * 8];
        #pragma unroll
        for (int j = 0; j < 4; j++)
            bfr[j] = *(const bf16x8*)&Bs[cur][(wn * 64 + j * 16 + col) * 32 + quad * 8];
        #pragma unroll
        for (int i = 0; i < 4; i++)
            #pragma unroll
            for (int j = 0; j < 4; j++)
                acc[i][j] = __builtin_amdgcn_mfma_f32_16x16x32_bf16(af[i], bfr[j], acc[i][j], 0, 0, 0);
        __syncthreads();
    }

    #pragma unroll
    for (int i = 0; i < 4; i++) {
        int mb = m0 + wm * 64 + i * 16 + quad * 4;
        #pragma unroll
        for (int j = 0; j < 4; j++) {
            int n = n0 + wn * 64 + j * 16 + col;
            if (EPI == 0 || EPI == 1) {
                float bs = bias[n];
                u16* Cb = (u16*)Cout;
                #pragma unroll
                for (int r = 0; r < 4; r++) {
                    float f = (acc[i][j][r] + bs) * ((EPI == 0) ? scale : 1.0f);
                    if (EPI == 1) f = fmaxf(f, 0.f);
                    Cb[(size_t)(mb + r) * N + n] = f2bf(f);
                }
            } else if (EPI == 2) {
                float bs = bias[n];
                float* Cf = (float*)Cout;
                #pragma unroll
                for (int r = 0; r < 4; r++)
                    Cf[(size_t)(mb + r) * N + n] =
                        acc[i][j][r] + bs + resid[(size_t)(mb + r) * N + n];
            } else if (EPI == 3) {
                float bs = bias[n];
                u16* Cb = (u16*)Cout;
                us4 pk;
                #pragma unroll
                for (int r = 0; r < 4; r++) pk[r] = f2bf(acc[i][j][r] + bs);
                *(us4*)&Cb[(size_t)n * M + mb] = pk;
            } else {
                float* Cf = (float*)Cout;
                #pragma unroll
                for (int r = 0; r < 4; r++)
                    atomicAdd(&Cf[(size_t)(mb + r) * N + n], acc[i][j][r]);
            }
        }
    }
}

template<int EPI>
__global__ __launch_bounds__(256) void gemm_kernel(const u16* __restrict__ A,
                                                   const u16* __restrict__ Wt,
                                                   const float* __restrict__ bias,
                                                   const float* __restrict__ resid,
                                                   void* __restrict__ C,
                                                   int M, int N, int Kstride, int Kloop,
                                                   float scale) {
    const u16* Az = A  + (size_t)blockIdx.z * Kloop;
    const u16* Wz = Wt + (size_t)blockIdx.z * Kloop;
    gemm128_core<EPI>(Az, Wz, bias, resid, C, M, N, Kstride, Kloop, scale,
                      blockIdx.y, blockIdx.x);
}

// Fused QKV: z=0 -> q (pre-scaled by 0.125*log2e), z=1 -> k, z=2 -> vT.
__global__ __launch_bounds__(256) void qkv_kernel(const u16* __restrict__ h,
        const u16* __restrict__ wqT, const u16* __restrict__ wkT, const u16* __restrict__ wvT,
        const float* __restrict__ bq, const float* __restrict__ bk, const float* __restrict__ bv,
        u16* __restrict__ q, u16* __restrict__ k, u16* __restrict__ vT) {
    int z = blockIdx.z;
    if (z == 0)      gemm128_core<0>(h, wqT, bq, nullptr, q,  MTOT, DM, DM, DM, QSCALE, blockIdx.y, blockIdx.x);
    else if (z == 1) gemm128_core<0>(h, wkT, bk, nullptr, k,  MTOT, DM, DM, DM, 1.0f,   blockIdx.y, blockIdx.x);
    else             gemm128_core<3>(h, wvT, bv, nullptr, vT, MTOT, DM, DM, DM, 1.0f,   blockIdx.y, blockIdx.x);
}

// ---------------------------------------------------------------------------
// 64x64-tile GEMM (for narrow/latency-bound Wo). EPI=2 path.
// ---------------------------------------------------------------------------
template<int EPI>
__global__ __launch_bounds__(256) void gemm64_kernel(const u16* __restrict__ A,
                                                     const u16* __restrict__ Wt,
                                                     const float* __restrict__ bias,
                                                     const float* __restrict__ resid,
                                                     void* __restrict__ Cout,
                                                     int M, int N, int Kstride, int Kloop) {
    __shared__ __align__(16) u16 As[2][64 * 32];
    __shared__ __align__(16) u16 Bs[2][64 * 32];
    int t = threadIdx.x, ln = t & 63, w = t >> 6;
    int wm = w >> 1, wn = w & 1;
    int quad = ln >> 4, col = ln & 15;
    int m0 = blockIdx.y * 64, n0 = blockIdx.x * 64;

    f32x4 acc[2][2];
    const f32x4 zero = {0.f, 0.f, 0.f, 0.f};
    #pragma unroll
    for (int i = 0; i < 2; i++)
        #pragma unroll
        for (int j = 0; j < 2; j++) acc[i][j] = zero;

    const u16* Ag = A  + (size_t)(m0 + 16 * w + (ln >> 2)) * Kstride + (ln & 3) * 8;
    const u16* Bg = Wt + (size_t)(n0 + 16 * w + (ln >> 2)) * Kstride + (ln & 3) * 8;
    gld16(Ag, As[0] + w * 512);
    gld16(Bg, Bs[0] + w * 512);
    __syncthreads();

    for (int k0 = 0; k0 < Kloop; k0 += 32) {
        int cur = (k0 >> 5) & 1, nxt = cur ^ 1;
        if (k0 + 32 < Kloop) {
            gld16(Ag + k0 + 32, As[nxt] + w * 512);
            gld16(Bg + k0 + 32, Bs[nxt] + w * 512);
        }
        bf16x8 af[2], bfr[2];
        #pragma unroll
        for (int i = 0; i < 2; i++)
            af[i] = *(const bf16x8*)&As[cur][(wm * 32 + i * 16 + col) * 32 + quad * 8];
        #pragma unroll
        for (int j = 0; j < 2; j++)
            bfr[j] = *(const bf16x8*)&Bs[cur][(wn * 32 + j * 16 + col) * 32 + quad * 8];
        #pragma unroll
        for (int i = 0; i < 2; i++)
            #pragma unroll
            for (int j = 0; j < 2; j++)
                acc[i][j] = __builtin_amdgcn_mfma_f32_16x16x32_bf16(af[i], bfr[j], acc[i][j], 0, 0, 0);
        __syncthreads();
    }

    #pragma unroll
    for (int i = 0; i < 2; i++) {
        int mb = m0 + wm * 32 + i * 16 + quad * 4;
        #pragma unroll
        for (int j = 0; j < 2; j++) {
            int n = n0 + wn * 32 + j * 16 + col;
            float bs = bias[n];
            float* Cf = (float*)Cout;
            #pragma unroll
            for (int r = 0; r < 4; r++)
                Cf[(size_t)(mb + r) * N + n] =
                    acc[i][j][r] + bs + resid[(size_t)(mb + r) * N + n];
        }
    }
}

// ---------------------------------------------------------------------------
// bf16 MFMA flash attention, KEY-SPLIT formulation. Block = 4 waves, BQ=64.
// Wave (qh=w>>1, kh=w&1) owns 32 queries x 32 keys per 64-key tile:
// each wave reads only ITS K/V rows from LDS (4+4 b128 vs 8+8), halving the
// LDS read traffic that saturated R4 (216 KB/tile-slot ~ 97% of LDS BW).
// Fixed-max softmax in exp2 domain; mask folded into the MFMA accumulator
// init (pre-staged float bias, b128 broadcast — no cndmask); truncating
// v_perm bf16 pack. Cross-wave O/l reduction once at the end through the
// dead K/V LDS buffers.
// ---------------------------------------------------------------------------
__global__ __launch_bounds__(256) void attn_kernel(const u16* __restrict__ qg,
                                                   const u16* __restrict__ kg,
                                                   const u16* __restrict__ vTg,
                                                   const int* __restrict__ mask,
                                                   u16* __restrict__ ctx) {
    __shared__ __align__(16) u16 Qs[64 * 64];
    __shared__ __align__(16) u16 KV[4][64 * 64];     // [0..1]=K dbuf, [2..3]=V dbuf
    __shared__ __align__(16) u16 Ps[4][32 * 40];     // per-wave 32q x 32key, stride 40
    __shared__ __align__(16) float Msf[2][64];       // mask bias (0 / -1e9)
    __shared__ float Lp[64][2];                      // l partials [q][kh]
    int t = threadIdx.x, ln = t & 63, w = t >> 6;
    int quad = ln >> 4, col = ln & 15;
    int qh = w >> 1, kh = w & 1;
    int bh = blockIdx.x, qb = blockIdx.y;
    int b = bh / NH, h = bh - b * NH;
    int q0 = qb * 64;
    size_t qkbase = ((size_t)b * SLEN) * DM + h * DKH;
    size_t vbase  = ((size_t)h * DKH) * MTOT + (size_t)b * SLEN;

    int sw_st = (((ln & 7) ^ (ln >> 3)) * 8);        // staging-side swizzled chunk

    // stage Q + K/V tile 0 + mask 0 (wave w stages rows 16w..16w+15)
    {
        const u16* g0 = qg + qkbase + (size_t)(q0 + 16 * w + (ln >> 3)) * DM + sw_st;
        gld16(g0,          Qs + w * 1024);
        gld16(g0 + 8 * DM, Qs + w * 1024 + 512);
        const u16* kg0 = kg + qkbase + (size_t)(16 * w + (ln >> 3)) * DM + sw_st;
        gld16(kg0,          KV[0] + w * 1024);
        gld16(kg0 + 8 * DM, KV[0] + w * 1024 + 512);
        const u16* vg0 = vTg + vbase + (size_t)(16 * w + (ln >> 3)) * MTOT + sw_st;
        gld16(vg0,            KV[2] + w * 1024);
        gld16(vg0 + 8 * MTOT, KV[2] + w * 1024 + 512);
        if (t < 64) Msf[0][t] = mask[b * SLEN + t] ? 0.f : -1e9f;
    }
    __syncthreads();

    // hoisted Q B-frags: rows q = qh*32 + qg*16 + col
    bf16x8 bqf[2][2];
    #pragma unroll
    for (int qgi = 0; qgi < 2; qgi++) {
        int rq = qh * 32 + qgi * 16 + col;
        int cq = ((quad ^ (rq & 7)) * 8);
        bqf[qgi][0] = *(const bf16x8*)&Qs[rq * 64 + cq];
        bqf[qgi][1] = *(const bf16x8*)&Qs[rq * 64 + (cq ^ 32)];
    }

    // loop-carried prefetch pointers
    const u16* kpn = kg + qkbase + (size_t)(64 + 16 * w + (ln >> 3)) * DM + sw_st;
    const u16* vpn = vTg + vbase + (size_t)(16 * w + (ln >> 3)) * MTOT + 64 + sw_st;
    const int* mpn = mask + b * SLEN + 64 + t;

    float lacc[2] = {0.f, 0.f};                      // per-qg partial sum (q = col)
    f32x4 Ov[2][4];
    const f32x4 zero = {0.f, 0.f, 0.f, 0.f};
    #pragma unroll
    for (int qgi = 0; qgi < 2; qgi++)
        #pragma unroll
        for (int dg = 0; dg < 4; dg++) Ov[qgi][dg] = zero;
    u16* Psw = &Ps[w][0];

    for (int j0 = 0; j0 < SLEN; j0 += 64) {
        int cur = (j0 >> 6) & 1, nxt = cur ^ 1;
        if (j0 + 64 < SLEN) {
            gld16(kpn,            KV[nxt] + w * 1024);
            gld16(kpn + 8 * DM,   KV[nxt] + w * 1024 + 512);
            gld16(vpn,            KV[2 + nxt] + w * 1024);
            gld16(vpn + 8 * MTOT, KV[2 + nxt] + w * 1024 + 512);
            if (t < 64) Msf[nxt][t] = *mpn ? 0.f : -1e9f;
            kpn += 64 * DM; vpn += 64; mpn += 64;
        }

        // K A-frags: rows = keys kh*32 + kg*16 + col (only this wave's half)
        bf16x8 ak[2][2];
        #pragma unroll
        for (int kgi = 0; kgi < 2; kgi++) {
            int rk = kh * 32 + kgi * 16 + col;
            int ck = ((quad ^ (rk & 7)) * 8);
            ak[kgi][0] = *(const bf16x8*)&KV[cur][rk * 64 + ck];
            ak[kgi][1] = *(const bf16x8*)&KV[cur][rk * 64 + (ck ^ 32)];
        }
        // S^T tiles: keys x q; acc pre-seeded with mask bias; exp2; pack P
        #pragma unroll
        for (int kgi = 0; kgi < 2; kgi++) {
            f32x4 bias4 = *(const f32x4*)&Msf[cur][kh * 32 + kgi * 16 + quad * 4];
            #pragma unroll
            for (int qgi = 0; qgi < 2; qgi++) {
                f32x4 S = __builtin_amdgcn_mfma_f32_16x16x32_bf16(ak[kgi][0], bqf[qgi][0], bias4, 0, 0, 0);
                S       = __builtin_amdgcn_mfma_f32_16x16x32_bf16(ak[kgi][1], bqf[qgi][1], S,     0, 0, 0);
                float p0 = exp2f(S[0]), p1 = exp2f(S[1]);
                float p2 = exp2f(S[2]), p3 = exp2f(S[3]);
                lacc[qgi] += (p0 + p1) + (p2 + p3);
                uint2 pk;
                pk.x = pk2bf_t(p0, p1);
                pk.y = pk2bf_t(p2, p3);
                *(uint2*)&Psw[(qgi * 16 + col) * 40 + kgi * 16 + quad * 4] = pk;
            }
        }
        // P A-frags (k = this wave's 32 keys)
        bf16x8 ap[2];
        #pragma unroll
        for (int qgi = 0; qgi < 2; qgi++)
            ap[qgi] = *(const bf16x8*)&Psw[(qgi * 16 + col) * 40 + quad * 8];
        // O += P·V over this wave's keys
        #pragma unroll
        for (int dg = 0; dg < 4; dg++) {
            int rv = dg * 16 + col;
            int cv = (((kh * 4 + quad) ^ (rv & 7)) * 8);
            bf16x8 bv = *(const bf16x8*)&KV[2 + cur][rv * 64 + cv];
            Ov[0][dg] = __builtin_amdgcn_mfma_f32_16x16x32_bf16(ap[0], bv, Ov[0][dg], 0, 0, 0);
            Ov[1][dg] = __builtin_amdgcn_mfma_f32_16x16x32_bf16(ap[1], bv, Ov[1][dg], 0, 0, 0);
        }
        __syncthreads();
    }

    // ---- cross-wave reduction (kh halves) through dead K/V LDS ----
    #pragma unroll
    for (int qgi = 0; qgi < 2; qgi++) {
        lacc[qgi] += __shfl_xor(lacc[qgi], 16);
        lacc[qgi] += __shfl_xor(lacc[qgi], 32);
        if (quad == 0) Lp[qh * 32 + qgi * 16 + col][kh] = lacc[qgi];
    }
    float* Osh = (float*)&KV[0][0];                  // [qh][64 d][36] fp32 (18.4 KB)
    if (kh == 1) {
        #pragma unroll
        for (int qgi = 0; qgi < 2; qgi++)
            #pragma unroll
            for (int dg = 0; dg < 4; dg++)
                *(f32x4*)&Osh[(qh * 64 + dg * 16 + col) * 36 + qgi * 16 + quad * 4] = Ov[qgi][dg];
    }
    __syncthreads();
    if (kh == 0) {
        #pragma unroll
        for (int qgi = 0; qgi < 2; qgi++) {
            float linv[4];
            #pragma unroll
            for (int r = 0; r < 4; r++) {
                int ql = qh * 32 + qgi * 16 + quad * 4 + r;
                linv[r] = 1.0f / (Lp[ql][0] + Lp[ql][1]);
            }
            #pragma unroll
            for (int dg = 0; dg < 4; dg++) {
                f32x4 oo = *(const f32x4*)&Osh[(qh * 64 + dg * 16 + col) * 36 + qgi * 16 + quad * 4];
                #pragma unroll
                for (int r = 0; r < 4; r++) {
                    int qrow = q0 + qh * 32 + qgi * 16 + quad * 4 + r;
                    ctx[qkbase + (size_t)qrow * DM + dg * 16 + col] =
                        f2bf((Ov[qgi][dg][r] + oo[r]) * linv[r]);
                }
            }
        }
    }
}

// ---------------------------------------------------------------------------
extern "C" void kernel_launch(void* const* d_in, const int* in_sizes, int n_in,
                              void* d_out, int out_size, void* d_ws, size_t ws_size,
                              hipStream_t stream) {
    const float* x    = (const float*)d_in[0];
    const int*   mask = (const int*)d_in[1];
    const float* wq   = (const float*)d_in[2];
    const float* bq   = (const float*)d_in[3];
    const float* wk   = (const float*)d_in[4];
    const float* bk   = (const float*)d_in[5];
    const float* wv   = (const float*)d_in[6];
    const float* bv   = (const float*)d_in[7];
    const float* wo   = (const float*)d_in[8];
    const float* bo   = (const float*)d_in[9];
    const float* w1   = (const float*)d_in[10];
    const float* b1   = (const float*)d_in[11];
    const float* w2   = (const float*)d_in[12];
    const float* b2   = (const float*)d_in[13];
    const float* ln1a = (const float*)d_in[14];
    const float* ln1b = (const float*)d_in[15];
    const float* ln2a = (const float*)d_in[16];
    const float* ln2b = (const float*)d_in[17];
    float* out = (float*)d_out;

    // workspace layout (bytes); ffn overlays q/k/vT/ctx (dead by FFN1)
    char* w8 = (char*)d_ws;
    u16*   ffn = (u16*)(w8 + 0);          // [4096][3072] bf16
    u16*   q   = (u16*)(w8 + 0);          // [4096][768] bf16 (pre-scaled)
    u16*   kb  = (u16*)(w8 + 6291456);
    u16*   vT  = (u16*)(w8 + 12582912);   // [768][4096] bf16
    u16*   ctx = (u16*)(w8 + 18874368);
    u16*   h   = (u16*)(w8 + 25165824);   // [4096][768] bf16
    float* x1  = (float*)(w8 + 31457280); // [4096][768] fp32
    u16*   wqT = (u16*)(w8 + 44040192);
    u16*   wkT = (u16*)(w8 + 45219840);
    u16*   wvT = (u16*)(w8 + 46399488);
    u16*   woT = (u16*)(w8 + 47579136);
    u16*   w1T = (u16*)(w8 + 48758784);   // [3072][768]
    u16*   w2T = (u16*)(w8 + 53477376);   // [768][3072]

    // 0. all weights -> bf16 transposed, single launch
    wcast_all<<<6912, 256, 0, stream>>>(wq, wk, wv, wo, w1, w2,
                                        wqT, wkT, wvT, woT, w1T, w2T);
    // 1. h = LN1(x)
    ln_kernel<<<MTOT, 256, 0, stream>>>(x, h, ln1a, ln1b, nullptr, nullptr);
    // 2. q (pre-scaled), k row-major; v transposed
    qkv_kernel<<<dim3(6, 32, 3), 256, 0, stream>>>(h, wqT, wkT, wvT, bq, bk, bv, q, kb, vT);
    // 3. ctx = flash-attention; grid (bh, qb) for XCD K/V locality
    attn_kernel<<<dim3(BATCH * NH, SLEN / 64), 256, 0, stream>>>(q, kb, vT, mask, ctx);
    // 4. x1 = x + ctx @ wo + bo
    gemm64_kernel<2><<<dim3(12, 64), 256, 0, stream>>>(ctx, woT, bo, x, (void*)x1,
                                                       MTOT, DM, DM, DM);
    // 5. h = LN2(x1), fused: out = x1 + b2 (seed for FFN2 atomics)
    ln_kernel<<<MTOT, 256, 0, stream>>>(x1, h, ln2a, ln2b, b2, out);
    // 6. ffn = relu(h @ w1 + b1)
    gemm_kernel<1><<<dim3(24, 32), 256, 0, stream>>>(h, w1T, b1, nullptr, (void*)ffn,
                                                     MTOT, DFF, DM, DM, 1.0f);
    // 7. out += ffn @ w2 (split-K=2, atomic)
    gemm_kernel<5><<<dim3(6, 32, 2), 256, 0, stream>>>(ffn, w2T, nullptr, nullptr, (void*)out,
                                                       MTOT, DM, DFF, DFF / 2, 1.0f);
}

// Round 6
// 294.623 us; speedup vs baseline: 5.4521x; 1.0015x over previous
//
#include <hip/hip_runtime.h>
#include <math.h>

#define DM    768
#define NH    12
#define DKH   64
#define DFF   3072
#define BATCH 2
#define SLEN  2048
#define MTOT  4096
#define LNEPS 1e-6f
#define QSCALE 0.18033688011112042f   // 0.125 * log2(e): softmax in exp2 domain

typedef unsigned short u16;
typedef __attribute__((ext_vector_type(8))) short bf16x8;   // MFMA A/B frag (4 VGPRs)
typedef __attribute__((ext_vector_type(4))) float f32x4;    // MFMA C/D frag
typedef __attribute__((ext_vector_type(4))) unsigned short us4;

__device__ __forceinline__ u16 f2bf(float f) {              // RNE float->bf16
    union { float f; unsigned int u; } v; v.f = f;
    unsigned int r = v.u + 0x7FFFu + ((v.u >> 16) & 1u);
    return (u16)(r >> 16);
}

// pack two floats -> two bf16 (TRUNCATED) in one u32 via v_perm_b32
__device__ __forceinline__ unsigned pk2bf_t(float lo, float hi) {
    union { float f; unsigned u; } a, b;
    a.f = lo; b.f = hi;
    return __builtin_amdgcn_perm(b.u, a.u, 0x07060302u);
}

// async global->LDS, 16 B per lane. LDS dest = wave-uniform base + lane*16.
__device__ __forceinline__ void gld16(const void* g, void* lds) {
    __builtin_amdgcn_global_load_lds(
        (const __attribute__((address_space(1))) unsigned int*)(unsigned long long)g,
        (__attribute__((address_space(3))) unsigned int*)(unsigned int)(unsigned long long)lds,
        16, 0, 0);
}

// ---------------------------------------------------------------------------
// LayerNorm fp32 in -> bf16 out. One block per row, 256 threads, 3 elems each.
// Optional fused epilogue (LN2): out2[row] = x[row] + b2 (fp32).
// ---------------------------------------------------------------------------
__global__ __launch_bounds__(256) void ln_kernel(const float* __restrict__ x,
                                                 u16* __restrict__ out,
                                                 const float* __restrict__ alpha_p,
                                                 const float* __restrict__ beta_p,
                                                 const float* __restrict__ b2,
                                                 float* __restrict__ out2) {
    int row = blockIdx.x;
    const float* xr = x + (size_t)row * DM;
    int t = threadIdx.x;
    float v0 = xr[t], v1 = xr[t + 256], v2 = xr[t + 512];
    float s = v0 + v1 + v2;
    #pragma unroll
    for (int off = 32; off > 0; off >>= 1) s += __shfl_down(s, off);
    __shared__ float red[4], red2[4];
    int wv = t >> 6, ln = t & 63;
    if (ln == 0) red[wv] = s;
    __syncthreads();
    float mean = (red[0] + red[1] + red[2] + red[3]) * (1.0f / 768.0f);
    float d0 = v0 - mean, d1 = v1 - mean, d2 = v2 - mean;
    float sq = d0 * d0 + d1 * d1 + d2 * d2;
    #pragma unroll
    for (int off = 32; off > 0; off >>= 1) sq += __shfl_down(sq, off);
    if (ln == 0) red2[wv] = sq;
    __syncthreads();
    float var = (red2[0] + red2[1] + red2[2] + red2[3]) * (1.0f / 767.0f); // ddof=1
    float scale = alpha_p[0] / (sqrtf(var) + LNEPS);
    float bias = beta_p[0];
    u16* orow = out + (size_t)row * DM;
    orow[t]       = f2bf(d0 * scale + bias);
    orow[t + 256] = f2bf(d1 * scale + bias);
    orow[t + 512] = f2bf(d2 * scale + bias);
    if (out2) {
        float* o2 = out2 + (size_t)row * DM;
        o2[t]       = v0 + b2[t];
        o2[t + 256] = v1 + b2[t + 256];
        o2[t + 512] = v2 + b2[t + 512];
    }
}

// ---------------------------------------------------------------------------
// Fused weight cast+transpose: all six weights in ONE launch (6912 tiles).
// ---------------------------------------------------------------------------
__global__ __launch_bounds__(256) void wcast_all(
        const float* __restrict__ wq, const float* __restrict__ wk,
        const float* __restrict__ wv, const float* __restrict__ wo,
        const float* __restrict__ w1, const float* __restrict__ w2,
        u16* __restrict__ wqT, u16* __restrict__ wkT, u16* __restrict__ wvT,
        u16* __restrict__ woT, u16* __restrict__ w1T, u16* __restrict__ w2T) {
    __shared__ float tile[32][33];
    int bid = blockIdx.x;
    const float* src; u16* dst; int R, C, bx, by;
    if (bid < 2304) {
        int j = bid / 576, tix = bid % 576;
        R = 768; C = 768; bx = tix % 24; by = tix / 24;
        src = (j == 0) ? wq : (j == 1) ? wk : (j == 2) ? wv : wo;
        dst = (j == 0) ? wqT : (j == 1) ? wkT : (j == 2) ? wvT : woT;
    } else if (bid < 4608) {
        int tix = bid - 2304;
        R = 768; C = 3072; bx = tix % 96; by = tix / 96;
        src = w1; dst = w1T;
    } else {
        int tix = bid - 4608;
        R = 3072; C = 768; bx = tix % 24; by = tix / 24;
        src = w2; dst = w2T;
    }
    int t = threadIdx.x, tx = t & 31, ty = t >> 5;
    int r0 = by * 32, c0 = bx * 32;
    #pragma unroll
    for (int p = 0; p < 4; p++)
        tile[ty + p * 8][tx] = src[(size_t)(r0 + ty + p * 8) * C + c0 + tx];
    __syncthreads();
    #pragma unroll
    for (int p = 0; p < 4; p++)
        dst[(size_t)(c0 + ty + p * 8) * R + r0 + tx] = f2bf(tile[tx][ty + p * 8]);
}

// ---------------------------------------------------------------------------
// bf16 MFMA GEMM core, 128x128 tile, BK=32, double-buffered staging.
// LDS rows are 32 u16 (64 B = 4 x 16B chunks). XOR-SWIZZLE: stored chunk p of
// row r holds source chunk p ^ ((r>>1)&3); frag reads use chunk
// quad ^ ((col>>1)&3). Bank walk: word addr = col*16 + 4*ch -> 8 four-bank
// groups x 2 lanes = 2-way (free). Without this, col*16 mod 32 in {0,16}
// made every ds_read_b128 8-way conflicted.
// EPI: 0 = bf16 out *scale, 1 = bf16 relu, 2 = fp32 + resid,
//      3 = bf16 transposed (dst[n][m]), 5 = fp32 atomicAdd (split-K)
// ---------------------------------------------------------------------------
template<int EPI>
__device__ __forceinline__ void gemm128_core(const u16* __restrict__ A,
                                             const u16* __restrict__ Wt,
                                             const float* __restrict__ bias,
                                             const float* __restrict__ resid,
                                             void* __restrict__ Cout,
                                             int M, int N, int Kstride, int Kloop,
                                             float scale, int bm, int bn) {
    __shared__ __align__(16) u16 As[2][128 * 32];
    __shared__ __align__(16) u16 Bs[2][128 * 32];
    int t = threadIdx.x;
    int ln = t & 63, w = t >> 6;
    int wm = w >> 1, wn = w & 1;
    int quad = ln >> 4, col = ln & 15;
    int m0 = bm * 128, n0 = bn * 128;

    f32x4 acc[4][4];
    const f32x4 zero = {0.f, 0.f, 0.f, 0.f};
    #pragma unroll
    for (int i = 0; i < 4; i++)
        #pragma unroll
        for (int j = 0; j < 4; j++) acc[i][j] = zero;

    // staging: lane ln covers row 32w + (ln>>2), LDS chunk ln&3; source chunk
    // is XOR-swizzled so reads land conflict-free. (row>>1)&3 == (ln>>3)&3.
    int st_ch = (((ln & 3) ^ ((ln >> 3) & 3))) * 8;
    const u16* Ag = A  + (size_t)(m0 + 32 * w + (ln >> 2)) * Kstride + st_ch;
    const u16* Bg = Wt + (size_t)(n0 + 32 * w + (ln >> 2)) * Kstride + st_ch;

    gld16(Ag,                As[0] + w * 1024);
    gld16(Ag + 16 * Kstride, As[0] + w * 1024 + 512);
    gld16(Bg,                Bs[0] + w * 1024);
    gld16(Bg + 16 * Kstride, Bs[0] + w * 1024 + 512);
    __syncthreads();

    int rch = (quad ^ ((col >> 1) & 3)) * 8;       // swizzled read chunk

    for (int k0 = 0; k0 < Kloop; k0 += 32) {
        int cur = (k0 >> 5) & 1, nxt = cur ^ 1;
        if (k0 + 32 < Kloop) {
            gld16(Ag + k0 + 32,                As[nxt] + w * 1024);
            gld16(Ag + k0 + 32 + 16 * Kstride, As[nxt] + w * 1024 + 512);
            gld16(Bg + k0 + 32,                Bs[nxt] + w * 1024);
            gld16(Bg + k0 + 32 + 16 * Kstride, Bs[nxt] + w * 1024 + 512);
        }
        bf16x8 af[4], bfr[4];
        #pragma unroll
        for (int i = 0; i < 4; i++)
            af[i] = *(const bf16x8*)&As[cur][(wm * 64 + i * 16 + col) * 32 + rch];
        #pragma unroll
        for (int j = 0; j < 4; j++)
            bfr[j] = *(const bf16x8*)&Bs[cur][(wn * 64 + j * 16 + col) * 32 + rch];
        #pragma unroll
        for (int i = 0; i < 4; i++)
            #pragma unroll
            for (int j = 0; j < 4; j++)
                acc[i][j] = __builtin_amdgcn_mfma_f32_16x16x32_bf16(af[i], bfr[j], acc[i][j], 0, 0, 0);
        __syncthreads();
    }

    #pragma unroll
    for (int i = 0; i < 4; i++) {
        int mb = m0 + wm * 64 + i * 16 + quad * 4;
        #pragma unroll
        for (int j = 0; j < 4; j++) {
            int n = n0 + wn * 64 + j * 16 + col;
            if (EPI == 0 || EPI == 1) {
                float bs = bias[n];
                u16* Cb = (u16*)Cout;
                #pragma unroll
                for (int r = 0; r < 4; r++) {
                    float f = (acc[i][j][r] + bs) * ((EPI == 0) ? scale : 1.0f);
                    if (EPI == 1) f = fmaxf(f, 0.f);
                    Cb[(size_t)(mb + r) * N + n] = f2bf(f);
                }
            } else if (EPI == 2) {
                float bs = bias[n];
                float* Cf = (float*)Cout;
                #pragma unroll
                for (int r = 0; r < 4; r++)
                    Cf[(size_t)(mb + r) * N + n] =
                        acc[i][j][r] + bs + resid[(size_t)(mb + r) * N + n];
            } else if (EPI == 3) {
                float bs = bias[n];
                u16* Cb = (u16*)Cout;
                us4 pk;
                #pragma unroll
                for (int r = 0; r < 4; r++) pk[r] = f2bf(acc[i][j][r] + bs);
                *(us4*)&Cb[(size_t)n * M + mb] = pk;
            } else {
                float* Cf = (float*)Cout;
                #pragma unroll
                for (int r = 0; r < 4; r++)
                    atomicAdd(&Cf[(size_t)(mb + r) * N + n], acc[i][j][r]);
            }
        }
    }
}

template<int EPI>
__global__ __launch_bounds__(256) void gemm_kernel(const u16* __restrict__ A,
                                                   const u16* __restrict__ Wt,
                                                   const float* __restrict__ bias,
                                                   const float* __restrict__ resid,
                                                   void* __restrict__ C,
                                                   int M, int N, int Kstride, int Kloop,
                                                   float scale) {
    const u16* Az = A  + (size_t)blockIdx.z * Kloop;
    const u16* Wz = Wt + (size_t)blockIdx.z * Kloop;
    gemm128_core<EPI>(Az, Wz, bias, resid, C, M, N, Kstride, Kloop, scale,
                      blockIdx.y, blockIdx.x);
}

// Fused QKV: z=0 -> q (pre-scaled by 0.125*log2e), z=1 -> k, z=2 -> vT.
__global__ __launch_bounds__(256) void qkv_kernel(const u16* __restrict__ h,
        const u16* __restrict__ wqT, const u16* __restrict__ wkT, const u16* __restrict__ wvT,
        const float* __restrict__ bq, const float* __restrict__ bk, const float* __restrict__ bv,
        u16* __restrict__ q, u16* __restrict__ k, u16* __restrict__ vT) {
    int z = blockIdx.z;
    if (z == 0)      gemm128_core<0>(h, wqT, bq, nullptr, q,  MTOT, DM, DM, DM, QSCALE, blockIdx.y, blockIdx.x);
    else if (z == 1) gemm128_core<0>(h, wkT, bk, nullptr, k,  MTOT, DM, DM, DM, 1.0f,   blockIdx.y, blockIdx.x);
    else             gemm128_core<3>(h, wvT, bv, nullptr, vT, MTOT, DM, DM, DM, 1.0f,   blockIdx.y, blockIdx.x);
}

// ---------------------------------------------------------------------------
// 64x64-tile GEMM (for narrow/latency-bound Wo). EPI=2 path. Same XOR swizzle.
// ---------------------------------------------------------------------------
template<int EPI>
__global__ __launch_bounds__(256) void gemm64_kernel(const u16* __restrict__ A,
                                                     const u16* __restrict__ Wt,
                                                     const float* __restrict__ bias,
                                                     const float* __restrict__ resid,
                                                     void* __restrict__ Cout,
                                                     int M, int N, int Kstride, int Kloop) {
    __shared__ __align__(16) u16 As[2][64 * 32];
    __shared__ __align__(16) u16 Bs[2][64 * 32];
    int t = threadIdx.x, ln = t & 63, w = t >> 6;
    int wm = w >> 1, wn = w & 1;
    int quad = ln >> 4, col = ln & 15;
    int m0 = blockIdx.y * 64, n0 = blockIdx.x * 64;

    f32x4 acc[2][2];
    const f32x4 zero = {0.f, 0.f, 0.f, 0.f};
    #pragma unroll
    for (int i = 0; i < 2; i++)
        #pragma unroll
        for (int j = 0; j < 2; j++) acc[i][j] = zero;

    int st_ch = (((ln & 3) ^ ((ln >> 3) & 3))) * 8;
    const u16* Ag = A  + (size_t)(m0 + 16 * w + (ln >> 2)) * Kstride + st_ch;
    const u16* Bg = Wt + (size_t)(n0 + 16 * w + (ln >> 2)) * Kstride + st_ch;
    gld16(Ag, As[0] + w * 512);
    gld16(Bg, Bs[0] + w * 512);
    __syncthreads();

    int rch = (quad ^ ((col >> 1) & 3)) * 8;

    for (int k0 = 0; k0 < Kloop; k0 += 32) {
        int cur = (k0 >> 5) & 1, nxt = cur ^ 1;
        if (k0 + 32 < Kloop) {
            gld16(Ag + k0 + 32, As[nxt] + w * 512);
            gld16(Bg + k0 + 32, Bs[nxt] + w * 512);
        }
        bf16x8 af[2], bfr[2];
        #pragma unroll
        for (int i = 0; i < 2; i++)
            af[i] = *(const bf16x8*)&As[cur][(wm * 32 + i * 16 + col) * 32 + rch];
        #pragma unroll
        for (int j = 0; j < 2; j++)
            bfr[j] = *(const bf16x8*)&Bs[cur][(wn * 32 + j * 16 + col) * 32 + rch];
        #pragma unroll
        for (int i = 0; i < 2; i++)
            #pragma unroll
            for (int j = 0; j < 2; j++)
                acc[i][j] = __builtin_amdgcn_mfma_f32_16x16x32_bf16(af[i], bfr[j], acc[i][j], 0, 0, 0);
        __syncthreads();
    }

    #pragma unroll
    for (int i = 0; i < 2; i++) {
        int mb = m0 + wm * 32 + i * 16 + quad * 4;
        #pragma unroll
        for (int j = 0; j < 2; j++) {
            int n = n0 + wn * 32 + j * 16 + col;
            float bs = bias[n];
            float* Cf = (float*)Cout;
            #pragma unroll
            for (int r = 0; r < 4; r++)
                Cf[(size_t)(mb + r) * N + n] =
                    acc[i][j][r] + bs + resid[(size_t)(mb + r) * N + n];
        }
    }
}

// ---------------------------------------------------------------------------
// bf16 MFMA flash attention, KEY-SPLIT formulation (unchanged from R5).
// ---------------------------------------------------------------------------
__global__ __launch_bounds__(256) void attn_kernel(const u16* __restrict__ qg,
                                                   const u16* __restrict__ kg,
                                                   const u16* __restrict__ vTg,
                                                   const int* __restrict__ mask,
                                                   u16* __restrict__ ctx) {
    __shared__ __align__(16) u16 Qs[64 * 64];
    __shared__ __align__(16) u16 KV[4][64 * 64];     // [0..1]=K dbuf, [2..3]=V dbuf
    __shared__ __align__(16) u16 Ps[4][32 * 40];     // per-wave 32q x 32key, stride 40
    __shared__ __align__(16) float Msf[2][64];       // mask bias (0 / -1e9)
    __shared__ float Lp[64][2];                      // l partials [q][kh]
    int t = threadIdx.x, ln = t & 63, w = t >> 6;
    int quad = ln >> 4, col = ln & 15;
    int qh = w >> 1, kh = w & 1;
    int bh = blockIdx.x, qb = blockIdx.y;
    int b = bh / NH, h = bh - b * NH;
    int q0 = qb * 64;
    size_t qkbase = ((size_t)b * SLEN) * DM + h * DKH;
    size_t vbase  = ((size_t)h * DKH) * MTOT + (size_t)b * SLEN;

    int sw_st = (((ln & 7) ^ (ln >> 3)) * 8);        // staging-side swizzled chunk

    // stage Q + K/V tile 0 + mask 0 (wave w stages rows 16w..16w+15)
    {
        const u16* g0 = qg + qkbase + (size_t)(q0 + 16 * w + (ln >> 3)) * DM + sw_st;
        gld16(g0,          Qs + w * 1024);
        gld16(g0 + 8 * DM, Qs + w * 1024 + 512);
        const u16* kg0 = kg + qkbase + (size_t)(16 * w + (ln >> 3)) * DM + sw_st;
        gld16(kg0,          KV[0] + w * 1024);
        gld16(kg0 + 8 * DM, KV[0] + w * 1024 + 512);
        const u16* vg0 = vTg + vbase + (size_t)(16 * w + (ln >> 3)) * MTOT + sw_st;
        gld16(vg0,            KV[2] + w * 1024);
        gld16(vg0 + 8 * MTOT, KV[2] + w * 1024 + 512);
        if (t < 64) Msf[0][t] = mask[b * SLEN + t] ? 0.f : -1e9f;
    }
    __syncthreads();

    // hoisted Q B-frags: rows q = qh*32 + qg*16 + col
    bf16x8 bqf[2][2];
    #pragma unroll
    for (int qgi = 0; qgi < 2; qgi++) {
        int rq = qh * 32 + qgi * 16 + col;
        int cq = ((quad ^ (rq & 7)) * 8);
        bqf[qgi][0] = *(const bf16x8*)&Qs[rq * 64 + cq];
        bqf[qgi][1] = *(const bf16x8*)&Qs[rq * 64 + (cq ^ 32)];
    }

    // loop-carried prefetch pointers
    const u16* kpn = kg + qkbase + (size_t)(64 + 16 * w + (ln >> 3)) * DM + sw_st;
    const u16* vpn = vTg + vbase + (size_t)(16 * w + (ln >> 3)) * MTOT + 64 + sw_st;
    const int* mpn = mask + b * SLEN + 64 + t;

    float lacc[2] = {0.f, 0.f};                      // per-qg partial sum (q = col)
    f32x4 Ov[2][4];
    const f32x4 zero = {0.f, 0.f, 0.f, 0.f};
    #pragma unroll
    for (int qgi = 0; qgi < 2; qgi++)
        #pragma unroll
        for (int dg = 0; dg < 4; dg++) Ov[qgi][dg] = zero;
    u16* Psw = &Ps[w][0];

    for (int j0 = 0; j0 < SLEN; j0 += 64) {
        int cur = (j0 >> 6) & 1, nxt = cur ^ 1;
        if (j0 + 64 < SLEN) {
            gld16(kpn,            KV[nxt] + w * 1024);
            gld16(kpn + 8 * DM,   KV[nxt] + w * 1024 + 512);
            gld16(vpn,            KV[2 + nxt] + w * 1024);
            gld16(vpn + 8 * MTOT, KV[2 + nxt] + w * 1024 + 512);
            if (t < 64) Msf[nxt][t] = *mpn ? 0.f : -1e9f;
            kpn += 64 * DM; vpn += 64; mpn += 64;
        }

        // K A-frags: rows = keys kh*32 + kg*16 + col (only this wave's half)
        bf16x8 ak[2][2];
        #pragma unroll
        for (int kgi = 0; kgi < 2; kgi++) {
            int rk = kh * 32 + kgi * 16 + col;
            int ck = ((quad ^ (rk & 7)) * 8);
            ak[kgi][0] = *(const bf16x8*)&KV[cur][rk * 64 + ck];
            ak[kgi][1] = *(const bf16x8*)&KV[cur][rk * 64 + (ck ^ 32)];
        }
        // S^T tiles: keys x q; acc pre-seeded with mask bias; exp2; pack P
        #pragma unroll
        for (int kgi = 0; kgi < 2; kgi++) {
            f32x4 bias4 = *(const f32x4*)&Msf[cur][kh * 32 + kgi * 16 + quad * 4];
            #pragma unroll
            for (int qgi = 0; qgi < 2; qgi++) {
                f32x4 S = __builtin_amdgcn_mfma_f32_16x16x32_bf16(ak[kgi][0], bqf[qgi][0], bias4, 0, 0, 0);
                S       = __builtin_amdgcn_mfma_f32_16x16x32_bf16(ak[kgi][1], bqf[qgi][1], S,     0, 0, 0);
                float p0 = exp2f(S[0]), p1 = exp2f(S[1]);
                float p2 = exp2f(S[2]), p3 = exp2f(S[3]);
                lacc[qgi] += (p0 + p1) + (p2 + p3);
                uint2 pk;
                pk.x = pk2bf_t(p0, p1);
                pk.y = pk2bf_t(p2, p3);
                *(uint2*)&Psw[(qgi * 16 + col) * 40 + kgi * 16 + quad * 4] = pk;
            }
        }
        // P A-frags (k = this wave's 32 keys)
        bf16x8 ap[2];
        #pragma unroll
        for (int qgi = 0; qgi < 2; qgi++)
            ap[qgi] = *(const bf16x8*)&Psw[(qgi * 16 + col) * 40 + quad * 8];
        // O += P·V over this wave's keys
        #pragma unroll
        for (int dg = 0; dg < 4; dg++) {
            int rv = dg * 16 + col;
            int cv = (((kh * 4 + quad) ^ (rv & 7)) * 8);
            bf16x8 bv = *(const bf16x8*)&KV[2 + cur][rv * 64 + cv];
            Ov[0][dg] = __builtin_amdgcn_mfma_f32_16x16x32_bf16(ap[0], bv, Ov[0][dg], 0, 0, 0);
            Ov[1][dg] = __builtin_amdgcn_mfma_f32_16x16x32_bf16(ap[1], bv, Ov[1][dg], 0, 0, 0);
        }
        __syncthreads();
    }

    // ---- cross-wave reduction (kh halves) through dead K/V LDS ----
    #pragma unroll
    for (int qgi = 0; qgi < 2; qgi++) {
        lacc[qgi] += __shfl_xor(lacc[qgi], 16);
        lacc[qgi] += __shfl_xor(lacc[qgi], 32);
        if (quad == 0) Lp[qh * 32 + qgi * 16 + col][kh] = lacc[qgi];
    }
    float* Osh = (float*)&KV[0][0];                  // [qh][64 d][36] fp32 (18.4 KB)
    if (kh == 1) {
        #pragma unroll
        for (int qgi = 0; qgi < 2; qgi++)
            #pragma unroll
            for (int dg = 0; dg < 4; dg++)
                *(f32x4*)&Osh[(qh * 64 + dg * 16 + col) * 36 + qgi * 16 + quad * 4] = Ov[qgi][dg];
    }
    __syncthreads();
    if (kh == 0) {
        #pragma unroll
        for (int qgi = 0; qgi < 2; qgi++) {
            float linv[4];
            #pragma unroll
            for (int r = 0; r < 4; r++) {
                int ql = qh * 32 + qgi * 16 + quad * 4 + r;
                linv[r] = 1.0f / (Lp[ql][0] + Lp[ql][1]);
            }
            #pragma unroll
            for (int dg = 0; dg < 4; dg++) {
                f32x4 oo = *(const f32x4*)&Osh[(qh * 64 + dg * 16 + col) * 36 + qgi * 16 + quad * 4];
                #pragma unroll
                for (int r = 0; r < 4; r++) {
                    int qrow = q0 + qh * 32 + qgi * 16 + quad * 4 + r;
                    ctx[qkbase + (size_t)qrow * DM + dg * 16 + col] =
                        f2bf((Ov[qgi][dg][r] + oo[r]) * linv[r]);
                }
            }
        }
    }
}

// ---------------------------------------------------------------------------
extern "C" void kernel_launch(void* const* d_in, const int* in_sizes, int n_in,
                              void* d_out, int out_size, void* d_ws, size_t ws_size,
                              hipStream_t stream) {
    const float* x    = (const float*)d_in[0];
    const int*   mask = (const int*)d_in[1];
    const float* wq   = (const float*)d_in[2];
    const float* bq   = (const float*)d_in[3];
    const float* wk   = (const float*)d_in[4];
    const float* bk   = (const float*)d_in[5];
    const float* wv   = (const float*)d_in[6];
    const float* bv   = (const float*)d_in[7];
    const float* wo   = (const float*)d_in[8];
    const float* bo   = (const float*)d_in[9];
    const float* w1   = (const float*)d_in[10];
    const float* b1   = (const float*)d_in[11];
    const float* w2   = (const float*)d_in[12];
    const float* b2   = (const float*)d_in[13];
    const float* ln1a = (const float*)d_in[14];
    const float* ln1b = (const float*)d_in[15];
    const float* ln2a = (const float*)d_in[16];
    const float* ln2b = (const float*)d_in[17];
    float* out = (float*)d_out;

    // workspace layout (bytes); ffn overlays q/k/vT/ctx (dead by FFN1)
    char* w8 = (char*)d_ws;
    u16*   ffn = (u16*)(w8 + 0);          // [4096][3072] bf16
    u16*   q   = (u16*)(w8 + 0);          // [4096][768] bf16 (pre-scaled)
    u16*   kb  = (u16*)(w8 + 6291456);
    u16*   vT  = (u16*)(w8 + 12582912);   // [768][4096] bf16
    u16*   ctx = (u16*)(w8 + 18874368);
    u16*   h   = (u16*)(w8 + 25165824);   // [4096][768] bf16
    float* x1  = (float*)(w8 + 31457280); // [4096][768] fp32
    u16*   wqT = (u16*)(w8 + 44040192);
    u16*   wkT = (u16*)(w8 + 45219840);
    u16*   wvT = (u16*)(w8 + 46399488);
    u16*   woT = (u16*)(w8 + 47579136);
    u16*   w1T = (u16*)(w8 + 48758784);   // [3072][768]
    u16*   w2T = (u16*)(w8 + 53477376);   // [768][3072]

    // 0. all weights -> bf16 transposed, single launch
    wcast_all<<<6912, 256, 0, stream>>>(wq, wk, wv, wo, w1, w2,
                                        wqT, wkT, wvT, woT, w1T, w2T);
    // 1. h = LN1(x)
    ln_kernel<<<MTOT, 256, 0, stream>>>(x, h, ln1a, ln1b, nullptr, nullptr);
    // 2. q (pre-scaled), k row-major; v transposed
    qkv_kernel<<<dim3(6, 32, 3), 256, 0, stream>>>(h, wqT, wkT, wvT, bq, bk, bv, q, kb, vT);
    // 3. ctx = flash-attention; grid (bh, qb) for XCD K/V locality
    attn_kernel<<<dim3(BATCH * NH, SLEN / 64), 256, 0, stream>>>(q, kb, vT, mask, ctx);
    // 4. x1 = x + ctx @ wo + bo
    gemm64_kernel<2><<<dim3(12, 64), 256, 0, stream>>>(ctx, woT, bo, x, (void*)x1,
                                                       MTOT, DM, DM, DM);
    // 5. h = LN2(x1), fused: out = x1 + b2 (seed for FFN2 atomics)
    ln_kernel<<<MTOT, 256, 0, stream>>>(x1, h, ln2a, ln2b, b2, out);
    // 6. ffn = relu(h @ w1 + b1)
    gemm_kernel<1><<<dim3(24, 32), 256, 0, stream>>>(h, w1T, b1, nullptr, (void*)ffn,
                                                     MTOT, DFF, DM, DM, 1.0f);
    // 7. out += ffn @ w2 (split-K=2, atomic)
    gemm_kernel<5><<<dim3(6, 32, 2), 256, 0, stream>>>(ffn, w2T, nullptr, nullptr, (void*)out,
                                                       MTOT, DM, DFF, DFF / 2, 1.0f);
}